// Round 13
// baseline (629.559 us; speedup 1.0000x reference)
//
#include <hip/hip_runtime.h>

// Problem constants
constexpr int kE = 65536, kNTOT = 8192;

// ---------------- threefry2x32 (JAX-exact, 20 rounds) ----------------
__host__ __device__ __forceinline__ void tf_round(unsigned& x0, unsigned& x1, int r) {
  x0 += x1;
  x1 = (x1 << r) | (x1 >> (32 - r));
  x1 ^= x0;
}
__host__ __device__ __forceinline__ void tf2x32(unsigned k0, unsigned k1,
                                                unsigned& x0, unsigned& x1) {
  unsigned ks2 = k0 ^ k1 ^ 0x1BD11BDAu;
  x0 += k0; x1 += k1;
  tf_round(x0,x1,13); tf_round(x0,x1,15); tf_round(x0,x1,26); tf_round(x0,x1,6);
  x0 += k1; x1 += ks2 + 1u;
  tf_round(x0,x1,17); tf_round(x0,x1,29); tf_round(x0,x1,16); tf_round(x0,x1,24);
  x0 += ks2; x1 += k0 + 2u;
  tf_round(x0,x1,13); tf_round(x0,x1,15); tf_round(x0,x1,26); tf_round(x0,x1,6);
  x0 += k0; x1 += k1 + 3u;
  tf_round(x0,x1,17); tf_round(x0,x1,29); tf_round(x0,x1,16); tf_round(x0,x1,24);
  x0 += k1; x1 += ks2 + 4u;
  tf_round(x0,x1,13); tf_round(x0,x1,15); tf_round(x0,x1,26); tf_round(x0,x1,6);
  x0 += ks2; x1 += k0 + 5u;
}

// bits -> N(0,1), replicating jax.random.normal f32 path (partitionable threefry)
__device__ __forceinline__ float bits_to_normal(unsigned bits) {
  float f = __uint_as_float((bits >> 9) | 0x3f800000u) - 1.0f;  // [0,1)
  const float LO = -0.99999994f;
  float u = fmaf(f, 2.0f, LO);
  u = fmaxf(u, LO);
  float w = -log1pf(-u * u);
  float p;
  if (w < 5.0f) {
    w -= 2.5f;
    p = 2.81022636e-08f;
    p = fmaf(p, w, 3.43273939e-07f);
    p = fmaf(p, w, -3.5233877e-06f);
    p = fmaf(p, w, -4.39150654e-06f);
    p = fmaf(p, w, 0.00021858087f);
    p = fmaf(p, w, -0.00125372503f);
    p = fmaf(p, w, -0.00417768164f);
    p = fmaf(p, w, 0.246640727f);
    p = fmaf(p, w, 1.50140941f);
  } else {
    w = sqrtf(w) - 3.0f;
    p = -0.000200214257f;
    p = fmaf(p, w, 0.000100950558f);
    p = fmaf(p, w, 0.00134934322f);
    p = fmaf(p, w, -0.00367342844f);
    p = fmaf(p, w, 0.00573950773f);
    p = fmaf(p, w, -0.0076224613f);
    p = fmaf(p, w, 0.00943887047f);
    p = fmaf(p, w, 1.00167406f);
    p = fmaf(p, w, 2.83297682f);
  }
  return 1.41421356f * (p * u);
}

__device__ __forceinline__ float redmax32(float v) {
#pragma unroll
  for (int o = 16; o > 0; o >>= 1) v = fmaxf(v, __shfl_xor(v, o));
  return v;
}
__device__ __forceinline__ float redsum32(float v) {
#pragma unroll
  for (int o = 16; o > 0; o >>= 1) v += __shfl_xor(v, o);
  return v;
}

// ====== shared softmax-producer tail: batch-aligned RNG + partial rfp (atomics) ======
// smem tail layout: sProb[16][132] @0, srr[16][33] @2112. Caller synced before.
__device__ __forceinline__ void rfp_tail(float* sm, int b, int r0, int t,
                                         float* __restrict__ rfr,
                                         float* __restrict__ rfp,
                                         unsigned fk0, unsigned fk1) {
  // RNG: this tile's 512 normals (rows r0..r0+15, 32 each); counter = global index
  unsigned base = (unsigned)(b * 4096 + r0 * 32);
#pragma unroll
  for (int q = 0; q < 2; ++q) {
    int il = t * 2 + q;
    unsigned a0 = 0u, a1 = base + (unsigned)il;
    tf2x32(fk0, fk1, a0, a1);
    float nv = bits_to_normal(a0 ^ a1);
    sm[2112 + (il >> 5) * 33 + (il & 31)] = nv;
    rfr[base + il] = nv;
  }
  __syncthreads();
  // partial rfp[p][ih..ih+16) += sum_{lr<16} sProb[lr][p] * srr[lr][ih..]
  int p = t >> 1, ih = (t & 1) * 16;
  float acc[16] = {};
#pragma unroll
  for (int lr = 0; lr < 16; ++lr) {
    float m = sm[lr * 132 + p];
    const float* rrr = &sm[2112 + lr * 33 + ih];
#pragma unroll
    for (int i = 0; i < 16; ++i) acc[i] = fmaf(m, rrr[i], acc[i]);
  }
  float* dst = rfp + ((size_t)(b * 128 + p)) * 32 + ih;
#pragma unroll
  for (int i = 0; i < 16; ++i) unsafeAtomicAdd(dst + i, acc[i]);
}

// ================= CSR build (multi-block) + agg & rfp zeroing =================
__global__ __launch_bounds__(256) void hist_kern(const int* __restrict__ eiR,
                                                 const int* __restrict__ eiP,
                                                 int* __restrict__ offR,
                                                 int* __restrict__ offP,
                                                 float* __restrict__ aggz,
                                                 float* __restrict__ rfpz) {
  int i = blockIdx.x * 256 + threadIdx.x;  // 0..131071
  float4 z4 = make_float4(0.f, 0.f, 0.f, 0.f);
  float4* z = reinterpret_cast<float4*>(aggz) + i * 2;
  z[0] = z4; z[1] = z4;
  reinterpret_cast<float2*>(rfpz)[i] = make_float2(0.f, 0.f);
  const int* ei = (i < kE) ? eiR : eiP;
  int* off = (i < kE) ? offR : offP;
  int e = i & (kE - 1);
  atomicAdd(&off[ei[kE + e]], 1);
}

__global__ __launch_bounds__(256) void scan_kern(int* __restrict__ offR,
                                                 int* __restrict__ offP) {
  int* off = blockIdx.x ? offP : offR;
  int t = threadIdx.x;
  int base = t * 32;
  int v[32];
#pragma unroll
  for (int i = 0; i < 32; ++i) v[i] = off[base + i];
  int sum = 0;
#pragma unroll
  for (int i = 0; i < 32; ++i) sum += v[i];
  int lane = t & 63, w = t >> 6;
  int incl = sum;
#pragma unroll
  for (int o = 1; o < 64; o <<= 1) {
    int y = __shfl_up(incl, o);
    if (lane >= o) incl += y;
  }
  __shared__ int wsum[4];
  if (lane == 63) wsum[w] = incl;
  __syncthreads();
  int woff = 0;
#pragma unroll
  for (int i = 0; i < 4; ++i) if (i < w) woff += wsum[i];
  int running = woff + incl - sum;
#pragma unroll
  for (int i = 0; i < 32; ++i) {
    off[base + i] = running;
    running += v[i];
  }
}

__global__ __launch_bounds__(256) void scatter_kern(
    const int* __restrict__ eiR, const int* __restrict__ eiP,
    int* __restrict__ offR, int* __restrict__ offP,
    int* __restrict__ permR, int* __restrict__ permP,
    int* __restrict__ srcsR, int* __restrict__ srcsP,
    int* __restrict__ dstsR, int* __restrict__ dstsP) {
  int i = blockIdx.x * 256 + threadIdx.x;
  const int* ei = (i < kE) ? eiR : eiP;
  int* off = (i < kE) ? offR : offP;
  int* perm = (i < kE) ? permR : permP;
  int* srcs = (i < kE) ? srcsR : srcsP;
  int* dsts = (i < kE) ? dstsR : dstsP;
  int e = i & (kE - 1);
  int dst = ei[kE + e];
  int pos = atomicAdd(&off[dst], 1);
  perm[pos] = e;
  srcs[pos] = ei[e];
  dsts[pos] = dst;
}

// ====== msg GEMM + fused segment-reduce aggregation (both graphs) [R10-verified] ======
template <int KX>
__global__ __launch_bounds__(256) void msg_gemm(
    const float* __restrict__ xR, const float* __restrict__ efR,
    const int* __restrict__ srcsR, const int* __restrict__ permR,
    const int* __restrict__ dstsR, float* __restrict__ aggR,
    const float* __restrict__ xP, const float* __restrict__ efP,
    const int* __restrict__ srcsP, const int* __restrict__ permP,
    const int* __restrict__ dstsP, float* __restrict__ aggP,
    const float* __restrict__ Wm, const float* __restrict__ We) {
  constexpr int KT = KX + 16;
  constexpr int SA_ROWS = (KT > 64) ? KT : 64;
  __shared__ float sA[SA_ROWS][68];
  __shared__ float sW[KT][68];
  __shared__ int sDst[64];
  bool isP = blockIdx.x >= 1024;
  const float* x = isP ? xP : xR;
  const float* ef = isP ? efP : efR;
  const int* srcs = isP ? srcsP : srcsR;
  const int* perm = isP ? permP : permR;
  const int* dsts = isP ? dstsP : dstsR;
  float* agg = isP ? aggP : aggR;
  int i0 = (blockIdx.x & 1023) * 64;
  int t = threadIdx.x;
#pragma unroll
  for (int idx = 0; idx < KT * 64 / 1024; ++idx) {
    int q = t * 4 + idx * 1024;
    int k = q >> 6, j = q & 63;
    const float* sp = (k < KX) ? (Wm + k * 64 + j) : (We + (k - KX) * 64 + j);
    float4 v = *reinterpret_cast<const float4*>(sp);
    *reinterpret_cast<float4*>(&sW[k][j]) = v;
  }
  if (t < 64) sDst[t] = dsts[i0 + t];
#pragma unroll
  for (int idx = 0; idx < KT * 64 / 1024; ++idx) {
    int q = t * 4 + idx * 1024;
    int r = q / KT;
    int k = q % KT;   // 4-aligned
    const float* rptr = (k < KX) ? (x + (size_t)srcs[i0 + r] * KX + k)
                                 : (ef + (size_t)perm[i0 + r] * 16 + (k - KX));
    float4 v = *reinterpret_cast<const float4*>(rptr);
    sA[k + 0][r] = v.x; sA[k + 1][r] = v.y; sA[k + 2][r] = v.z; sA[k + 3][r] = v.w;
  }
  __syncthreads();
  int tn = (t & 15) * 4;
  int tj = (t >> 4) * 4;
  float acc[4][4] = {};
#pragma unroll 8
  for (int k = 0; k < KT; ++k) {
    float4 a = *reinterpret_cast<const float4*>(&sA[k][tn]);
    float4 b = *reinterpret_cast<const float4*>(&sW[k][tj]);
    acc[0][0] = fmaf(a.x, b.x, acc[0][0]); acc[0][1] = fmaf(a.x, b.y, acc[0][1]);
    acc[0][2] = fmaf(a.x, b.z, acc[0][2]); acc[0][3] = fmaf(a.x, b.w, acc[0][3]);
    acc[1][0] = fmaf(a.y, b.x, acc[1][0]); acc[1][1] = fmaf(a.y, b.y, acc[1][1]);
    acc[1][2] = fmaf(a.y, b.z, acc[1][2]); acc[1][3] = fmaf(a.y, b.w, acc[1][3]);
    acc[2][0] = fmaf(a.z, b.x, acc[2][0]); acc[2][1] = fmaf(a.z, b.y, acc[2][1]);
    acc[2][2] = fmaf(a.z, b.z, acc[2][2]); acc[2][3] = fmaf(a.z, b.w, acc[2][3]);
    acc[3][0] = fmaf(a.w, b.x, acc[3][0]); acc[3][1] = fmaf(a.w, b.y, acc[3][1]);
    acc[3][2] = fmaf(a.w, b.z, acc[3][2]); acc[3][3] = fmaf(a.w, b.w, acc[3][3]);
  }
  __syncthreads();            // reuse sA as output tile [row][col]; float4 stores
#pragma unroll
  for (int i = 0; i < 4; ++i) {
    *reinterpret_cast<float4*>(&sA[tn + i][tj]) =
        make_float4(fmaxf(acc[i][0], 0.f), fmaxf(acc[i][1], 0.f),
                    fmaxf(acc[i][2], 0.f), fmaxf(acc[i][3], 0.f));
  }
  __syncthreads();
  int col = t & 63;
  int r0l = (t >> 6) * 16;
  float run = 0.f;
  int rd = sDst[r0l];
#pragma unroll
  for (int r = 0; r < 16; ++r) {
    int d = sDst[r0l + r];
    if (d != rd) {
      unsafeAtomicAdd(&agg[(size_t)rd * 64 + col], run);
      run = 0.f; rd = d;
    }
    run += sA[r0l + r][col];
  }
  unsafeAtomicAdd(&agg[(size_t)rd * 64 + col], run);
}

// ====== node1 dense tiled GEMM: h = relu(X@Ws + agg + b); re-zeroes agg ======
__global__ __launch_bounds__(256) void node1_gemm(
    const float* __restrict__ xR, float* __restrict__ aggR, float* __restrict__ hR,
    const float* __restrict__ xP, float* __restrict__ aggP, float* __restrict__ hP,
    const float* __restrict__ Ws, const float* __restrict__ bias) {
  __shared__ float sX[64][68];
  __shared__ float sW[64][68];
  bool isP = blockIdx.x >= 128;
  const float* x = isP ? xP : xR;
  float* agg = isP ? aggP : aggR;
  float* h = isP ? hP : hR;
  int n0 = (blockIdx.x & 127) * 64;
  int t = threadIdx.x;
#pragma unroll
  for (int idx = 0; idx < 4; ++idx) {
    int q = t * 4 + idx * 1024;
    int k = q >> 6, j = q & 63;
    *reinterpret_cast<float4*>(&sW[k][j]) = *reinterpret_cast<const float4*>(Ws + q);
    float4 v = *reinterpret_cast<const float4*>(x + (size_t)n0 * 64 + q);
    sX[j + 0][k] = v.x; sX[j + 1][k] = v.y; sX[j + 2][k] = v.z; sX[j + 3][k] = v.w;
  }
  __syncthreads();
  int tn = (t & 15) * 4, tj = (t >> 4) * 4;
  float acc[4][4] = {};
#pragma unroll 8
  for (int k = 0; k < 64; ++k) {
    float4 a = *reinterpret_cast<const float4*>(&sX[k][tn]);
    float4 b = *reinterpret_cast<const float4*>(&sW[k][tj]);
    acc[0][0] = fmaf(a.x, b.x, acc[0][0]); acc[0][1] = fmaf(a.x, b.y, acc[0][1]);
    acc[0][2] = fmaf(a.x, b.z, acc[0][2]); acc[0][3] = fmaf(a.x, b.w, acc[0][3]);
    acc[1][0] = fmaf(a.y, b.x, acc[1][0]); acc[1][1] = fmaf(a.y, b.y, acc[1][1]);
    acc[1][2] = fmaf(a.y, b.z, acc[1][2]); acc[1][3] = fmaf(a.y, b.w, acc[1][3]);
    acc[2][0] = fmaf(a.z, b.x, acc[2][0]); acc[2][1] = fmaf(a.z, b.y, acc[2][1]);
    acc[2][2] = fmaf(a.z, b.z, acc[2][2]); acc[2][3] = fmaf(a.z, b.w, acc[2][3]);
    acc[3][0] = fmaf(a.w, b.x, acc[3][0]); acc[3][1] = fmaf(a.w, b.y, acc[3][1]);
    acc[3][2] = fmaf(a.w, b.z, acc[3][2]); acc[3][3] = fmaf(a.w, b.w, acc[3][3]);
  }
  float4 bv = *reinterpret_cast<const float4*>(bias + tj);
  float4 z4 = make_float4(0.f, 0.f, 0.f, 0.f);
#pragma unroll
  for (int i = 0; i < 4; ++i) {
    int n = n0 + tn + i;
    float4 g = *reinterpret_cast<const float4*>(&agg[(size_t)n * 64 + tj]);
    *reinterpret_cast<float4*>(&agg[(size_t)n * 64 + tj]) = z4;
    float4 o;
    o.x = fmaxf(acc[i][0] + g.x + bv.x, 0.f);
    o.y = fmaxf(acc[i][1] + g.y + bv.y, 0.f);
    o.z = fmaxf(acc[i][2] + g.z + bv.z, 0.f);
    o.w = fmaxf(acc[i][3] + g.w + bv.w, 0.f);
    *reinterpret_cast<float4*>(&h[(size_t)n * 64 + tj]) = o;
  }
}

// ====== mhat_soft: Mhat tile + fused row softmax (->M0 out) + RNG + partial rfp ======
__global__ __launch_bounds__(256) void mhat_soft(
    const float* __restrict__ hR, const float* __restrict__ hP,
    float* __restrict__ Mhat, float* __restrict__ M0out,
    float* __restrict__ rfr, float* __restrict__ rfp,
    unsigned fk0, unsigned fk1) {
  __shared__ float sm[9504];   // hr[16][66]@0, hp[128][66]@1056 | tail: sProb/srr
  int gid = blockIdx.x, t = threadIdx.x;
  int b = gid >> 3, r0 = (gid & 7) * 16;
  const float* hrG = hR + ((size_t)(b * 128 + r0)) * 64;
  {
    int q = t * 4; int r = q >> 6, d = q & 63;
    float4 v = *reinterpret_cast<const float4*>(hrG + q);
    sm[r * 66 + d] = v.x; sm[r * 66 + d + 1] = v.y;
    sm[r * 66 + d + 2] = v.z; sm[r * 66 + d + 3] = v.w;
  }
  const float* hpG = hP + (size_t)b * 128 * 64;
#pragma unroll
  for (int rep = 0; rep < 8; ++rep) {
    int q = (rep * 256 + t) * 4; int p = q >> 6, d = q & 63;
    float4 v = *reinterpret_cast<const float4*>(hpG + q);
    sm[1056 + p * 66 + d] = v.x; sm[1056 + p * 66 + d + 1] = v.y;
    sm[1056 + p * 66 + d + 2] = v.z; sm[1056 + p * 66 + d + 3] = v.w;
  }
  __syncthreads();
  int tx = t & 31, ty = t >> 5;
  float acc[2][4] = {};
  for (int d = 0; d < 64; ++d) {
    float a0 = sm[ty * 66 + d], a1 = sm[(ty + 8) * 66 + d];
    float q0 = sm[1056 + tx * 66 + d], q1 = sm[1056 + (tx + 32) * 66 + d];
    float q2 = sm[1056 + (tx + 64) * 66 + d], q3 = sm[1056 + (tx + 96) * 66 + d];
    acc[0][0] = fmaf(a0, q0, acc[0][0]); acc[0][1] = fmaf(a0, q1, acc[0][1]);
    acc[0][2] = fmaf(a0, q2, acc[0][2]); acc[0][3] = fmaf(a0, q3, acc[0][3]);
    acc[1][0] = fmaf(a1, q0, acc[1][0]); acc[1][1] = fmaf(a1, q1, acc[1][1]);
    acc[1][2] = fmaf(a1, q2, acc[1][2]); acc[1][3] = fmaf(a1, q3, acc[1][3]);
  }
  float prob[2][4];
#pragma unroll
  for (int ii = 0; ii < 2; ++ii) {
    int r = r0 + ty + 8 * ii;
    float* mrow = Mhat + ((size_t)(b * 128 + r)) * 128;
    mrow[tx] = acc[ii][0]; mrow[tx + 32] = acc[ii][1];
    mrow[tx + 64] = acc[ii][2]; mrow[tx + 96] = acc[ii][3];
    float mx = redmax32(fmaxf(fmaxf(acc[ii][0], acc[ii][1]), fmaxf(acc[ii][2], acc[ii][3])));
    float e0 = __expf(acc[ii][0] - mx), e1 = __expf(acc[ii][1] - mx);
    float e2 = __expf(acc[ii][2] - mx), e3 = __expf(acc[ii][3] - mx);
    float inv = 1.0f / redsum32(e0 + e1 + e2 + e3);
    prob[ii][0] = e0 * inv; prob[ii][1] = e1 * inv;
    prob[ii][2] = e2 * inv; prob[ii][3] = e3 * inv;
    float* orow = M0out + ((size_t)(b * 128 + r)) * 128;
    orow[tx] = prob[ii][0]; orow[tx + 32] = prob[ii][1];
    orow[tx + 64] = prob[ii][2]; orow[tx + 96] = prob[ii][3];
  }
  __syncthreads();   // staging dead; reuse sm[0..2112) as sProb[16][132], srr @2112
#pragma unroll
  for (int ii = 0; ii < 2; ++ii) {
    int lr = ty + 8 * ii;
    sm[lr * 132 + tx] = prob[ii][0]; sm[lr * 132 + tx + 32] = prob[ii][1];
    sm[lr * 132 + tx + 64] = prob[ii][2]; sm[lr * 132 + tx + 96] = prob[ii][3];
  }
  // (no sync needed before RNG writes to srr; rfp_tail syncs before reading)
  rfp_tail(sm, b, r0, t, rfr, rfp, fk0, fk1);
}

// ====== node2u: o = relu(rf@Ws2 + agg + g2b); u = o@W1 (+b1); re-zeroes agg & rfp ======
__global__ __launch_bounds__(256) void node2u_gemm(
    const float* __restrict__ rfR, float* __restrict__ aggR, float* __restrict__ uR,
    float* __restrict__ rfP, float* __restrict__ aggP, float* __restrict__ uP,
    const float* __restrict__ Ws2, const float* __restrict__ g2b,
    const float* __restrict__ W1, const float* __restrict__ b1) {
  __shared__ float sRF[32][68];
  __shared__ float sW2[32][68];
  __shared__ float sW1[64][68];
  __shared__ float sO[64][68];
  bool isP = blockIdx.x >= 128;
  const float* rf = isP ? rfP : rfR;
  float* agg = isP ? aggP : aggR;
  float* u = isP ? uP : uR;
  int n0 = (blockIdx.x & 127) * 64;
  int t = threadIdx.x;
#pragma unroll
  for (int idx = 0; idx < 4; ++idx) {
    int q = t * 4 + idx * 1024;
    *reinterpret_cast<float4*>(&sW1[q >> 6][q & 63]) = *reinterpret_cast<const float4*>(W1 + q);
  }
#pragma unroll
  for (int idx = 0; idx < 2; ++idx) {
    int q = t * 4 + idx * 1024;
    *reinterpret_cast<float4*>(&sW2[q >> 6][q & 63]) = *reinterpret_cast<const float4*>(Ws2 + q);
    int r = q >> 5, kk = q & 31;
    float4 v = *reinterpret_cast<const float4*>(rf + (size_t)(n0 + r) * 32 + kk);
    sRF[kk][r] = v.x; sRF[kk + 1][r] = v.y; sRF[kk + 2][r] = v.z; sRF[kk + 3][r] = v.w;
  }
  __syncthreads();
  if (isP) {   // re-arm rfp for next iteration's atomic accumulation (reads done)
    float4 z4 = make_float4(0.f, 0.f, 0.f, 0.f);
#pragma unroll
    for (int idx = 0; idx < 2; ++idx) {
      int q = t * 4 + idx * 1024;
      *reinterpret_cast<float4*>(rfP + (size_t)n0 * 32 + q) = z4;
    }
  }
  int tn = (t & 15) * 4, tj = (t >> 4) * 4;
  float acc[4][4] = {};
#pragma unroll 8
  for (int k = 0; k < 32; ++k) {
    float4 a = *reinterpret_cast<const float4*>(&sRF[k][tn]);
    float4 b = *reinterpret_cast<const float4*>(&sW2[k][tj]);
    acc[0][0] = fmaf(a.x, b.x, acc[0][0]); acc[0][1] = fmaf(a.x, b.y, acc[0][1]);
    acc[0][2] = fmaf(a.x, b.z, acc[0][2]); acc[0][3] = fmaf(a.x, b.w, acc[0][3]);
    acc[1][0] = fmaf(a.y, b.x, acc[1][0]); acc[1][1] = fmaf(a.y, b.y, acc[1][1]);
    acc[1][2] = fmaf(a.y, b.z, acc[1][2]); acc[1][3] = fmaf(a.y, b.w, acc[1][3]);
    acc[2][0] = fmaf(a.z, b.x, acc[2][0]); acc[2][1] = fmaf(a.z, b.y, acc[2][1]);
    acc[2][2] = fmaf(a.z, b.z, acc[2][2]); acc[2][3] = fmaf(a.z, b.w, acc[2][3]);
    acc[3][0] = fmaf(a.w, b.x, acc[3][0]); acc[3][1] = fmaf(a.w, b.y, acc[3][1]);
    acc[3][2] = fmaf(a.w, b.z, acc[3][2]); acc[3][3] = fmaf(a.w, b.w, acc[3][3]);
  }
  float4 bg = *reinterpret_cast<const float4*>(g2b + tj);
  float4 z4 = make_float4(0.f, 0.f, 0.f, 0.f);
#pragma unroll
  for (int i = 0; i < 4; ++i) {
    int n = n0 + tn + i;
    float4 g = *reinterpret_cast<const float4*>(&agg[(size_t)n * 64 + tj]);
    *reinterpret_cast<float4*>(&agg[(size_t)n * 64 + tj]) = z4;
    sO[tj + 0][tn + i] = fmaxf(acc[i][0] + g.x + bg.x, 0.f);
    sO[tj + 1][tn + i] = fmaxf(acc[i][1] + g.y + bg.y, 0.f);
    sO[tj + 2][tn + i] = fmaxf(acc[i][2] + g.z + bg.z, 0.f);
    sO[tj + 3][tn + i] = fmaxf(acc[i][3] + g.w + bg.w, 0.f);
  }
  __syncthreads();
  float acc2[4][4] = {};
#pragma unroll 8
  for (int k = 0; k < 64; ++k) {
    float4 a = *reinterpret_cast<const float4*>(&sO[k][tn]);
    float4 b = *reinterpret_cast<const float4*>(&sW1[k][tj]);
    acc2[0][0] = fmaf(a.x, b.x, acc2[0][0]); acc2[0][1] = fmaf(a.x, b.y, acc2[0][1]);
    acc2[0][2] = fmaf(a.x, b.z, acc2[0][2]); acc2[0][3] = fmaf(a.x, b.w, acc2[0][3]);
    acc2[1][0] = fmaf(a.y, b.x, acc2[1][0]); acc2[1][1] = fmaf(a.y, b.y, acc2[1][1]);
    acc2[1][2] = fmaf(a.y, b.z, acc2[1][2]); acc2[1][3] = fmaf(a.y, b.w, acc2[1][3]);
    acc2[2][0] = fmaf(a.z, b.x, acc2[2][0]); acc2[2][1] = fmaf(a.z, b.y, acc2[2][1]);
    acc2[2][2] = fmaf(a.z, b.z, acc2[2][2]); acc2[2][3] = fmaf(a.z, b.w, acc2[2][3]);
    acc2[3][0] = fmaf(a.w, b.x, acc2[3][0]); acc2[3][1] = fmaf(a.w, b.y, acc2[3][1]);
    acc2[3][2] = fmaf(a.w, b.z, acc2[3][2]); acc2[3][3] = fmaf(a.w, b.w, acc2[3][3]);
  }
  float4 b1v = make_float4(0.f, 0.f, 0.f, 0.f);
  if (!isP) b1v = *reinterpret_cast<const float4*>(b1 + tj);
#pragma unroll
  for (int i = 0; i < 4; ++i) {
    int n = n0 + tn + i;
    float4 o;
    o.x = acc2[i][0] + b1v.x; o.y = acc2[i][1] + b1v.y;
    o.z = acc2[i][2] + b1v.z; o.w = acc2[i][3] + b1v.w;
    *reinterpret_cast<float4*>(&u[(size_t)n * 64 + tj]) = o;
  }
}

// ====== upd_soft: Mhat += pairwise MLP; softmax -> (out if last) else
//        (RNG + partial rfp for next iteration). 512 blocks. ======
__global__ __launch_bounds__(256) void upd_soft(
    const float* __restrict__ uR, const float* __restrict__ uP,
    const float* __restrict__ W2, const float* __restrict__ b2p,
    float* __restrict__ Mhat, float* __restrict__ outLast, int last,
    float* __restrict__ rfr, float* __restrict__ rfp,
    unsigned fk0, unsigned fk1) {
  __shared__ float sm[9568];   // sur[16][66]@0, sup[128][66]@1056, sw2@9504 | tail reuse
  int gid = blockIdx.x, t = threadIdx.x;
  int b = gid >> 3, r0 = (gid & 7) * 16;
  const float* urG = uR + ((size_t)(b * 128 + r0)) * 64;
  {
    int q = t * 4; int r = q >> 6, d = q & 63;
    float4 v = *reinterpret_cast<const float4*>(urG + q);
    sm[r * 66 + d] = v.x; sm[r * 66 + d + 1] = v.y;
    sm[r * 66 + d + 2] = v.z; sm[r * 66 + d + 3] = v.w;
  }
  const float* upG = uP + (size_t)b * 128 * 64;
#pragma unroll
  for (int rep = 0; rep < 8; ++rep) {
    int q = (rep * 256 + t) * 4; int p = q >> 6, d = q & 63;
    float4 v = *reinterpret_cast<const float4*>(upG + q);
    sm[1056 + p * 66 + d] = v.x; sm[1056 + p * 66 + d + 1] = v.y;
    sm[1056 + p * 66 + d + 2] = v.z; sm[1056 + p * 66 + d + 3] = v.w;
  }
  if (t < 64) sm[9504 + t] = W2[t];
  __syncthreads();
  int tx = t & 31, ty = t >> 5;
  float acc[2][4] = {};
  for (int j = 0; j < 64; ++j) {
    float w2v = sm[9504 + j];
    float a0 = sm[ty * 66 + j], a1 = sm[(ty + 8) * 66 + j];
    float q0 = sm[1056 + tx * 66 + j], q1 = sm[1056 + (tx + 32) * 66 + j];
    float q2 = sm[1056 + (tx + 64) * 66 + j], q3 = sm[1056 + (tx + 96) * 66 + j];
    acc[0][0] = fmaf(fmaxf(a0 - q0, 0.f), w2v, acc[0][0]);
    acc[0][1] = fmaf(fmaxf(a0 - q1, 0.f), w2v, acc[0][1]);
    acc[0][2] = fmaf(fmaxf(a0 - q2, 0.f), w2v, acc[0][2]);
    acc[0][3] = fmaf(fmaxf(a0 - q3, 0.f), w2v, acc[0][3]);
    acc[1][0] = fmaf(fmaxf(a1 - q0, 0.f), w2v, acc[1][0]);
    acc[1][1] = fmaf(fmaxf(a1 - q1, 0.f), w2v, acc[1][1]);
    acc[1][2] = fmaf(fmaxf(a1 - q2, 0.f), w2v, acc[1][2]);
    acc[1][3] = fmaf(fmaxf(a1 - q3, 0.f), w2v, acc[1][3]);
  }
  float b2v = b2p[0];
  float prob[2][4];
#pragma unroll
  for (int ii = 0; ii < 2; ++ii) {
    int r = r0 + ty + 8 * ii;
    float* mrow = Mhat + ((size_t)(b * 128 + r)) * 128;
    float m0 = mrow[tx] + acc[ii][0] + b2v;
    float m1 = mrow[tx + 32] + acc[ii][1] + b2v;
    float m2 = mrow[tx + 64] + acc[ii][2] + b2v;
    float m3 = mrow[tx + 96] + acc[ii][3] + b2v;
    if (!last) {
      mrow[tx] = m0; mrow[tx + 32] = m1; mrow[tx + 64] = m2; mrow[tx + 96] = m3;
    }
    float mx = redmax32(fmaxf(fmaxf(m0, m1), fmaxf(m2, m3)));
    float e0 = __expf(m0 - mx), e1 = __expf(m1 - mx);
    float e2 = __expf(m2 - mx), e3 = __expf(m3 - mx);
    float inv = 1.0f / redsum32(e0 + e1 + e2 + e3);
    prob[ii][0] = e0 * inv; prob[ii][1] = e1 * inv;
    prob[ii][2] = e2 * inv; prob[ii][3] = e3 * inv;
    if (last) {
      float* orow = outLast + ((size_t)(b * 128 + r)) * 128;
      orow[tx] = prob[ii][0]; orow[tx + 32] = prob[ii][1];
      orow[tx + 64] = prob[ii][2]; orow[tx + 96] = prob[ii][3];
    }
  }
  if (last) return;
  __syncthreads();   // staging dead; reuse sm as sProb[16][132] @0, srr @2112
#pragma unroll
  for (int ii = 0; ii < 2; ++ii) {
    int lr = ty + 8 * ii;
    sm[lr * 132 + tx] = prob[ii][0]; sm[lr * 132 + tx + 32] = prob[ii][1];
    sm[lr * 132 + tx + 64] = prob[ii][2]; sm[lr * 132 + tx + 96] = prob[ii][3];
  }
  rfp_tail(sm, b, r0, t, rfr, rfp, fk0, fk1);
}

extern "C" void kernel_launch(void* const* d_in, const int* in_sizes, int n_in,
                              void* d_out, int out_size, void* d_ws, size_t ws_size,
                              hipStream_t stream) {
  (void)in_sizes; (void)n_in; (void)out_size; (void)ws_size;
  const float* x_r  = (const float*)d_in[0];
  const int*   ei_r = (const int*)d_in[1];
  const float* ef_r = (const float*)d_in[2];
  const float* x_p  = (const float*)d_in[3];
  const int*   ei_p = (const int*)d_in[4];
  const float* ef_p = (const float*)d_in[5];
  const float* g1_Ws = (const float*)d_in[8];
  const float* g1_Wm = (const float*)d_in[9];
  const float* g1_We = (const float*)d_in[10];
  const float* g1_b  = (const float*)d_in[11];
  const float* g2_Ws = (const float*)d_in[12];
  const float* g2_Wm = (const float*)d_in[13];
  const float* g2_We = (const float*)d_in[14];
  const float* g2_b  = (const float*)d_in[15];
  const float* W1 = (const float*)d_in[16];
  const float* b1 = (const float*)d_in[17];
  const float* W2 = (const float*)d_in[18];
  const float* b2 = (const float*)d_in[19];
  float* out = (float*)d_out;

  float* ws = (float*)d_ws;
  float* h_r   = ws;                 // 524288
  float* h_p   = h_r + 524288;       // 524288
  float* Mhat  = h_p + 524288;       // 1048576
  float* rfr   = Mhat + 1048576;     // 262144
  float* rfp   = rfr + 262144;       // 262144
  float* u_r   = rfp + 262144;       // 524288
  float* u_p   = u_r + 524288;       // 524288
  float* agg_r = u_p + 524288;       // 524288
  float* agg_p = agg_r + 524288;     // 524288 (contiguous for zeroing)
  int* ib      = (int*)(agg_p + 524288);
  int* off_r  = ib;                  // 8192 (zeroed)
  int* off_p  = off_r + 8192;        // 8192
  int* perm_r = off_p + 8192;        // 65536
  int* perm_p = perm_r + 65536;      // 65536
  int* srcs_r = perm_p + 65536;      // 65536
  int* srcs_p = srcs_r + 65536;      // 65536
  int* dsts_r = srcs_p + 65536;      // 65536
  int* dsts_p = dsts_r + 65536;      // 65536

  unsigned fk0[3], fk1[3];
  for (int it = 0; it < 3; ++it) {
    unsigned a = 0u, c = (unsigned)it;
    tf2x32(0u, 42u, a, c);
    fk0[it] = a; fk1[it] = c;
  }

  // ---- CSR build + agg & rfp zeroing ----
  hipMemsetAsync(off_r, 0, 2 * 8192 * sizeof(int), stream);
  hist_kern<<<512, 256, 0, stream>>>(ei_r, ei_p, off_r, off_p, agg_r, rfp);
  scan_kern<<<2, 256, 0, stream>>>(off_r, off_p);
  scatter_kern<<<512, 256, 0, stream>>>(ei_r, ei_p, off_r, off_p,
                                        perm_r, perm_p, srcs_r, srcs_p,
                                        dsts_r, dsts_p);

  // ---- gnn1: msg GEMM (+agg atomics), node GEMM, Mhat+softmax+RNG+rfp ----
  msg_gemm<64><<<2048, 256, 0, stream>>>(x_r, ef_r, srcs_r, perm_r, dsts_r, agg_r,
                                         x_p, ef_p, srcs_p, perm_p, dsts_p, agg_p,
                                         g1_Wm, g1_We);
  node1_gemm<<<256, 256, 0, stream>>>(x_r, agg_r, h_r, x_p, agg_p, h_p, g1_Ws, g1_b);
  mhat_soft<<<512, 256, 0, stream>>>(h_r, h_p, Mhat, out, rfr, rfp, fk0[0], fk1[0]);

  for (int it = 0; it < 3; ++it) {
    msg_gemm<32><<<2048, 256, 0, stream>>>(rfr, ef_r, srcs_r, perm_r, dsts_r, agg_r,
                                           rfp, ef_p, srcs_p, perm_p, dsts_p, agg_p,
                                           g2_Wm, g2_We);
    node2u_gemm<<<256, 256, 0, stream>>>(rfr, agg_r, u_r, rfp, agg_p, u_p,
                                         g2_Ws, g2_b, W1, b1);
    int last = (it == 2);
    upd_soft<<<512, 256, 0, stream>>>(u_r, u_p, W2, b2, Mhat,
                                      out + 1048576, last, rfr, rfp,
                                      fk0[last ? 0 : it + 1], fk1[last ? 0 : it + 1]);
  }
}

// Round 14
// 312.565 us; speedup vs baseline: 2.0142x; 2.0142x over previous
//
#include <hip/hip_runtime.h>

// Problem constants
constexpr int kE = 65536, kNTOT = 8192;

// ---------------- threefry2x32 (JAX-exact, 20 rounds) ----------------
__host__ __device__ __forceinline__ void tf_round(unsigned& x0, unsigned& x1, int r) {
  x0 += x1;
  x1 = (x1 << r) | (x1 >> (32 - r));
  x1 ^= x0;
}
__host__ __device__ __forceinline__ void tf2x32(unsigned k0, unsigned k1,
                                                unsigned& x0, unsigned& x1) {
  unsigned ks2 = k0 ^ k1 ^ 0x1BD11BDAu;
  x0 += k0; x1 += k1;
  tf_round(x0,x1,13); tf_round(x0,x1,15); tf_round(x0,x1,26); tf_round(x0,x1,6);
  x0 += k1; x1 += ks2 + 1u;
  tf_round(x0,x1,17); tf_round(x0,x1,29); tf_round(x0,x1,16); tf_round(x0,x1,24);
  x0 += ks2; x1 += k0 + 2u;
  tf_round(x0,x1,13); tf_round(x0,x1,15); tf_round(x0,x1,26); tf_round(x0,x1,6);
  x0 += k0; x1 += k1 + 3u;
  tf_round(x0,x1,17); tf_round(x0,x1,29); tf_round(x0,x1,16); tf_round(x0,x1,24);
  x0 += k1; x1 += ks2 + 4u;
  tf_round(x0,x1,13); tf_round(x0,x1,15); tf_round(x0,x1,26); tf_round(x0,x1,6);
  x0 += ks2; x1 += k0 + 5u;
}

// bits -> N(0,1), replicating jax.random.normal f32 path (partitionable threefry)
__device__ __forceinline__ float bits_to_normal(unsigned bits) {
  float f = __uint_as_float((bits >> 9) | 0x3f800000u) - 1.0f;  // [0,1)
  const float LO = -0.99999994f;
  float u = fmaf(f, 2.0f, LO);
  u = fmaxf(u, LO);
  float w = -log1pf(-u * u);
  float p;
  if (w < 5.0f) {
    w -= 2.5f;
    p = 2.81022636e-08f;
    p = fmaf(p, w, 3.43273939e-07f);
    p = fmaf(p, w, -3.5233877e-06f);
    p = fmaf(p, w, -4.39150654e-06f);
    p = fmaf(p, w, 0.00021858087f);
    p = fmaf(p, w, -0.00125372503f);
    p = fmaf(p, w, -0.00417768164f);
    p = fmaf(p, w, 0.246640727f);
    p = fmaf(p, w, 1.50140941f);
  } else {
    w = sqrtf(w) - 3.0f;
    p = -0.000200214257f;
    p = fmaf(p, w, 0.000100950558f);
    p = fmaf(p, w, 0.00134934322f);
    p = fmaf(p, w, -0.00367342844f);
    p = fmaf(p, w, 0.00573950773f);
    p = fmaf(p, w, -0.0076224613f);
    p = fmaf(p, w, 0.00943887047f);
    p = fmaf(p, w, 1.00167406f);
    p = fmaf(p, w, 2.83297682f);
  }
  return 1.41421356f * (p * u);
}

__device__ __forceinline__ float redmax32(float v) {
#pragma unroll
  for (int o = 16; o > 0; o >>= 1) v = fmaxf(v, __shfl_xor(v, o));
  return v;
}
__device__ __forceinline__ float redsum32(float v) {
#pragma unroll
  for (int o = 16; o > 0; o >>= 1) v += __shfl_xor(v, o);
  return v;
}

// ================= CSR build (multi-block) + agg zeroing =================
__global__ __launch_bounds__(256) void hist_kern(const int* __restrict__ eiR,
                                                 const int* __restrict__ eiP,
                                                 int* __restrict__ offR,
                                                 int* __restrict__ offP,
                                                 float* __restrict__ aggz) {
  int i = blockIdx.x * 256 + threadIdx.x;  // 0..131071
  float4 z4 = make_float4(0.f, 0.f, 0.f, 0.f);
  float4* z = reinterpret_cast<float4*>(aggz) + i * 2;
  z[0] = z4; z[1] = z4;
  const int* ei = (i < kE) ? eiR : eiP;
  int* off = (i < kE) ? offR : offP;
  int e = i & (kE - 1);
  atomicAdd(&off[ei[kE + e]], 1);
}

// 2 blocks (one per graph): in-place exclusive scan of off[] (counts -> offsets)
__global__ __launch_bounds__(256) void scan_kern(int* __restrict__ offR,
                                                 int* __restrict__ offP) {
  int* off = blockIdx.x ? offP : offR;
  int t = threadIdx.x;
  int base = t * 32;
  int v[32];
#pragma unroll
  for (int i = 0; i < 32; ++i) v[i] = off[base + i];
  int sum = 0;
#pragma unroll
  for (int i = 0; i < 32; ++i) sum += v[i];
  int lane = t & 63, w = t >> 6;
  int incl = sum;
#pragma unroll
  for (int o = 1; o < 64; o <<= 1) {
    int y = __shfl_up(incl, o);
    if (lane >= o) incl += y;
  }
  __shared__ int wsum[4];
  if (lane == 63) wsum[w] = incl;
  __syncthreads();
  int woff = 0;
#pragma unroll
  for (int i = 0; i < 4; ++i) if (i < w) woff += wsum[i];
  int running = woff + incl - sum;
#pragma unroll
  for (int i = 0; i < 32; ++i) {
    off[base + i] = running;
    running += v[i];
  }
}

__global__ __launch_bounds__(256) void scatter_kern(
    const int* __restrict__ eiR, const int* __restrict__ eiP,
    int* __restrict__ offR, int* __restrict__ offP,
    int* __restrict__ permR, int* __restrict__ permP,
    int* __restrict__ srcsR, int* __restrict__ srcsP,
    int* __restrict__ dstsR, int* __restrict__ dstsP) {
  int i = blockIdx.x * 256 + threadIdx.x;
  const int* ei = (i < kE) ? eiR : eiP;
  int* off = (i < kE) ? offR : offP;
  int* perm = (i < kE) ? permR : permP;
  int* srcs = (i < kE) ? srcsR : srcsP;
  int* dsts = (i < kE) ? dstsR : dstsP;
  int e = i & (kE - 1);
  int dst = ei[kE + e];
  int pos = atomicAdd(&off[dst], 1);
  perm[pos] = e;
  srcs[pos] = ei[e];
  dsts[pos] = dst;
}

// ====== msg GEMM + fused segment-reduce aggregation (both graphs) ======
template <int KX>
__global__ __launch_bounds__(256) void msg_gemm(
    const float* __restrict__ xR, const float* __restrict__ efR,
    const int* __restrict__ srcsR, const int* __restrict__ permR,
    const int* __restrict__ dstsR, float* __restrict__ aggR,
    const float* __restrict__ xP, const float* __restrict__ efP,
    const int* __restrict__ srcsP, const int* __restrict__ permP,
    const int* __restrict__ dstsP, float* __restrict__ aggP,
    const float* __restrict__ Wm, const float* __restrict__ We) {
  constexpr int KT = KX + 16;
  constexpr int SA_ROWS = (KT > 64) ? KT : 64;
  __shared__ float sA[SA_ROWS][68];
  __shared__ float sW[KT][68];
  __shared__ int sDst[64];
  bool isP = blockIdx.x >= 1024;
  const float* x = isP ? xP : xR;
  const float* ef = isP ? efP : efR;
  const int* srcs = isP ? srcsP : srcsR;
  const int* perm = isP ? permP : permR;
  const int* dsts = isP ? dstsP : dstsR;
  float* agg = isP ? aggP : aggR;
  int i0 = (blockIdx.x & 1023) * 64;
  int t = threadIdx.x;
#pragma unroll
  for (int idx = 0; idx < KT * 64 / 1024; ++idx) {
    int q = t * 4 + idx * 1024;
    int k = q >> 6, j = q & 63;
    const float* sp = (k < KX) ? (Wm + k * 64 + j) : (We + (k - KX) * 64 + j);
    float4 v = *reinterpret_cast<const float4*>(sp);
    *reinterpret_cast<float4*>(&sW[k][j]) = v;
  }
  if (t < 64) sDst[t] = dsts[i0 + t];
#pragma unroll
  for (int idx = 0; idx < KT * 64 / 1024; ++idx) {
    int q = t * 4 + idx * 1024;
    int r = q / KT;
    int k = q % KT;   // 4-aligned
    const float* rptr = (k < KX) ? (x + (size_t)srcs[i0 + r] * KX + k)
                                 : (ef + (size_t)perm[i0 + r] * 16 + (k - KX));
    float4 v = *reinterpret_cast<const float4*>(rptr);
    sA[k + 0][r] = v.x; sA[k + 1][r] = v.y; sA[k + 2][r] = v.z; sA[k + 3][r] = v.w;
  }
  __syncthreads();
  int tn = (t & 15) * 4;
  int tj = (t >> 4) * 4;
  float acc[4][4] = {};
#pragma unroll 8
  for (int k = 0; k < KT; ++k) {
    float4 a = *reinterpret_cast<const float4*>(&sA[k][tn]);
    float4 b = *reinterpret_cast<const float4*>(&sW[k][tj]);
    acc[0][0] = fmaf(a.x, b.x, acc[0][0]); acc[0][1] = fmaf(a.x, b.y, acc[0][1]);
    acc[0][2] = fmaf(a.x, b.z, acc[0][2]); acc[0][3] = fmaf(a.x, b.w, acc[0][3]);
    acc[1][0] = fmaf(a.y, b.x, acc[1][0]); acc[1][1] = fmaf(a.y, b.y, acc[1][1]);
    acc[1][2] = fmaf(a.y, b.z, acc[1][2]); acc[1][3] = fmaf(a.y, b.w, acc[1][3]);
    acc[2][0] = fmaf(a.z, b.x, acc[2][0]); acc[2][1] = fmaf(a.z, b.y, acc[2][1]);
    acc[2][2] = fmaf(a.z, b.z, acc[2][2]); acc[2][3] = fmaf(a.z, b.w, acc[2][3]);
    acc[3][0] = fmaf(a.w, b.x, acc[3][0]); acc[3][1] = fmaf(a.w, b.y, acc[3][1]);
    acc[3][2] = fmaf(a.w, b.z, acc[3][2]); acc[3][3] = fmaf(a.w, b.w, acc[3][3]);
  }
  __syncthreads();            // reuse sA as output tile [row][col]; float4 stores
#pragma unroll
  for (int i = 0; i < 4; ++i) {
    *reinterpret_cast<float4*>(&sA[tn + i][tj]) =
        make_float4(fmaxf(acc[i][0], 0.f), fmaxf(acc[i][1], 0.f),
                    fmaxf(acc[i][2], 0.f), fmaxf(acc[i][3], 0.f));
  }
  __syncthreads();
  // segment-reduce: 64 cols x 4 row-chunks of 16; one atomic per dst-run per col
  int col = t & 63;
  int r0l = (t >> 6) * 16;
  float run = 0.f;
  int rd = sDst[r0l];
#pragma unroll
  for (int r = 0; r < 16; ++r) {
    int d = sDst[r0l + r];
    if (d != rd) {
      unsafeAtomicAdd(&agg[(size_t)rd * 64 + col], run);
      run = 0.f; rd = d;
    }
    run += sA[r0l + r][col];
  }
  unsafeAtomicAdd(&agg[(size_t)rd * 64 + col], run);
}

// ====== node1 dense tiled GEMM: h = relu(X@Ws + agg + b); re-zeroes agg ======
__global__ __launch_bounds__(256) void node1_gemm(
    const float* __restrict__ xR, float* __restrict__ aggR, float* __restrict__ hR,
    const float* __restrict__ xP, float* __restrict__ aggP, float* __restrict__ hP,
    const float* __restrict__ Ws, const float* __restrict__ bias) {
  __shared__ float sX[64][68];
  __shared__ float sW[64][68];
  bool isP = blockIdx.x >= 128;
  const float* x = isP ? xP : xR;
  float* agg = isP ? aggP : aggR;
  float* h = isP ? hP : hR;
  int n0 = (blockIdx.x & 127) * 64;
  int t = threadIdx.x;
#pragma unroll
  for (int idx = 0; idx < 4; ++idx) {
    int q = t * 4 + idx * 1024;
    int k = q >> 6, j = q & 63;
    *reinterpret_cast<float4*>(&sW[k][j]) = *reinterpret_cast<const float4*>(Ws + q);
    float4 v = *reinterpret_cast<const float4*>(x + (size_t)n0 * 64 + q);
    sX[j + 0][k] = v.x; sX[j + 1][k] = v.y; sX[j + 2][k] = v.z; sX[j + 3][k] = v.w;
  }
  __syncthreads();
  int tn = (t & 15) * 4, tj = (t >> 4) * 4;
  float acc[4][4] = {};
#pragma unroll 8
  for (int k = 0; k < 64; ++k) {
    float4 a = *reinterpret_cast<const float4*>(&sX[k][tn]);
    float4 b = *reinterpret_cast<const float4*>(&sW[k][tj]);
    acc[0][0] = fmaf(a.x, b.x, acc[0][0]); acc[0][1] = fmaf(a.x, b.y, acc[0][1]);
    acc[0][2] = fmaf(a.x, b.z, acc[0][2]); acc[0][3] = fmaf(a.x, b.w, acc[0][3]);
    acc[1][0] = fmaf(a.y, b.x, acc[1][0]); acc[1][1] = fmaf(a.y, b.y, acc[1][1]);
    acc[1][2] = fmaf(a.y, b.z, acc[1][2]); acc[1][3] = fmaf(a.y, b.w, acc[1][3]);
    acc[2][0] = fmaf(a.z, b.x, acc[2][0]); acc[2][1] = fmaf(a.z, b.y, acc[2][1]);
    acc[2][2] = fmaf(a.z, b.z, acc[2][2]); acc[2][3] = fmaf(a.z, b.w, acc[2][3]);
    acc[3][0] = fmaf(a.w, b.x, acc[3][0]); acc[3][1] = fmaf(a.w, b.y, acc[3][1]);
    acc[3][2] = fmaf(a.w, b.z, acc[3][2]); acc[3][3] = fmaf(a.w, b.w, acc[3][3]);
  }
  float4 bv = *reinterpret_cast<const float4*>(bias + tj);
  float4 z4 = make_float4(0.f, 0.f, 0.f, 0.f);
#pragma unroll
  for (int i = 0; i < 4; ++i) {
    int n = n0 + tn + i;
    float4 g = *reinterpret_cast<const float4*>(&agg[(size_t)n * 64 + tj]);
    *reinterpret_cast<float4*>(&agg[(size_t)n * 64 + tj]) = z4;  // re-arm for next iter
    float4 o;
    o.x = fmaxf(acc[i][0] + g.x + bv.x, 0.f);
    o.y = fmaxf(acc[i][1] + g.y + bv.y, 0.f);
    o.z = fmaxf(acc[i][2] + g.z + bv.z, 0.f);
    o.w = fmaxf(acc[i][3] + g.w + bv.w, 0.f);
    *reinterpret_cast<float4*>(&h[(size_t)n * 64 + tj]) = o;
  }
}

// ====== mhat_soft: Mhat tile + fused row softmax (->Msoft, ->out M0) + it0 RNG ======
__global__ __launch_bounds__(256) void mhat_soft(
    const float* __restrict__ hR, const float* __restrict__ hP,
    float* __restrict__ Mhat, float* __restrict__ Msoft, float* __restrict__ M0out,
    float* __restrict__ rfr, unsigned fk0, unsigned fk1) {
  __shared__ float hr[16][66];
  __shared__ float hp[128][66];
  int gid = blockIdx.x, t = threadIdx.x;
  int gtid = (gid << 8) + t;
#pragma unroll
  for (int q = 0; q < 2; ++q) {
    unsigned i = (unsigned)gtid + (unsigned)q * 131072u;
    unsigned a0 = 0u, a1 = i;
    tf2x32(fk0, fk1, a0, a1);
    rfr[i] = bits_to_normal(a0 ^ a1);
  }
  int b = gid >> 3, r0 = (gid & 7) * 16;
  const float* hrG = hR + ((size_t)(b * 128 + r0)) * 64;
  {
    int q = t * 4; int r = q >> 6, d = q & 63;
    float4 v = *reinterpret_cast<const float4*>(hrG + q);
    hr[r][d] = v.x; hr[r][d + 1] = v.y; hr[r][d + 2] = v.z; hr[r][d + 3] = v.w;
  }
  const float* hpG = hP + (size_t)b * 128 * 64;
#pragma unroll
  for (int rep = 0; rep < 8; ++rep) {
    int q = (rep * 256 + t) * 4; int p = q >> 6, d = q & 63;
    float4 v = *reinterpret_cast<const float4*>(hpG + q);
    hp[p][d] = v.x; hp[p][d + 1] = v.y; hp[p][d + 2] = v.z; hp[p][d + 3] = v.w;
  }
  __syncthreads();
  int tx = t & 31, ty = t >> 5;
  float acc[2][4] = {};
  for (int d = 0; d < 64; ++d) {
    float a0 = hr[ty][d], a1 = hr[ty + 8][d];
    float q0 = hp[tx][d], q1 = hp[tx + 32][d], q2 = hp[tx + 64][d], q3 = hp[tx + 96][d];
    acc[0][0] = fmaf(a0, q0, acc[0][0]); acc[0][1] = fmaf(a0, q1, acc[0][1]);
    acc[0][2] = fmaf(a0, q2, acc[0][2]); acc[0][3] = fmaf(a0, q3, acc[0][3]);
    acc[1][0] = fmaf(a1, q0, acc[1][0]); acc[1][1] = fmaf(a1, q1, acc[1][1]);
    acc[1][2] = fmaf(a1, q2, acc[1][2]); acc[1][3] = fmaf(a1, q3, acc[1][3]);
  }
#pragma unroll
  for (int ii = 0; ii < 2; ++ii) {
    int r = r0 + ty + 8 * ii;
    float* mrow = Mhat + ((size_t)(b * 128 + r)) * 128;
    mrow[tx] = acc[ii][0]; mrow[tx + 32] = acc[ii][1];
    mrow[tx + 64] = acc[ii][2]; mrow[tx + 96] = acc[ii][3];
    float mx = redmax32(fmaxf(fmaxf(acc[ii][0], acc[ii][1]), fmaxf(acc[ii][2], acc[ii][3])));
    float e0 = __expf(acc[ii][0] - mx), e1 = __expf(acc[ii][1] - mx);
    float e2 = __expf(acc[ii][2] - mx), e3 = __expf(acc[ii][3] - mx);
    float inv = 1.0f / redsum32(e0 + e1 + e2 + e3);
    float* srow = Msoft + ((size_t)(b * 128 + r)) * 128;
    srow[tx] = e0 * inv; srow[tx + 32] = e1 * inv;
    srow[tx + 64] = e2 * inv; srow[tx + 96] = e3 * inv;
    float* orow = M0out + ((size_t)(b * 128 + r)) * 128;
    orow[tx] = e0 * inv; orow[tx + 32] = e1 * inv;
    orow[tx + 64] = e2 * inv; orow[tx + 96] = e3 * inv;
  }
}

// ====== rfp: rfp[b,p,i] = sum_r Msoft[b,r,p] * rfr[b,r,i]  (512 blocks) ======
__global__ __launch_bounds__(256) void rfp_kern(
    const float* __restrict__ Msoft, const float* __restrict__ rfr,
    float* __restrict__ rfp) {
  __shared__ float rr[128][36];
  int b = blockIdx.x >> 3, p0 = (blockIdx.x & 7) * 16;
  int t = threadIdx.x;
  const float* rfG = rfr + (size_t)b * 4096;
#pragma unroll
  for (int rep = 0; rep < 4; ++rep) {
    int q = (rep * 256 + t) * 4; int r = q >> 5, i = q & 31;
    float4 v = *reinterpret_cast<const float4*>(rfG + q);
    rr[r][i] = v.x; rr[r][i + 1] = v.y; rr[r][i + 2] = v.z; rr[r][i + 3] = v.w;
  }
  __syncthreads();
  int pl = t & 15, ih = (t >> 4) * 2;
  int p = p0 + pl;
  const float* Mcol = Msoft + (size_t)b * 16384 + p;
  float a0 = 0.f, a1 = 0.f;
#pragma unroll 8
  for (int r = 0; r < 128; ++r) {
    float m = Mcol[(size_t)r * 128];
    a0 = fmaf(m, rr[r][ih], a0);
    a1 = fmaf(m, rr[r][ih + 1], a1);
  }
  float* dst = rfp + ((size_t)(b * 128 + p)) * 32 + ih;
  dst[0] = a0; dst[1] = a1;
}

// ====== node2u: o = relu(rf@Ws2 + agg + g2b); u = o@W1 (+b1); re-zeroes agg ======
__global__ __launch_bounds__(256) void node2u_gemm(
    const float* __restrict__ rfR, float* __restrict__ aggR, float* __restrict__ uR,
    const float* __restrict__ rfP, float* __restrict__ aggP, float* __restrict__ uP,
    const float* __restrict__ Ws2, const float* __restrict__ g2b,
    const float* __restrict__ W1, const float* __restrict__ b1) {
  __shared__ float sRF[32][68];
  __shared__ float sW2[32][68];
  __shared__ float sW1[64][68];
  __shared__ float sO[64][68];
  bool isP = blockIdx.x >= 128;
  const float* rf = isP ? rfP : rfR;
  float* agg = isP ? aggP : aggR;
  float* u = isP ? uP : uR;
  int n0 = (blockIdx.x & 127) * 64;
  int t = threadIdx.x;
#pragma unroll
  for (int idx = 0; idx < 4; ++idx) {
    int q = t * 4 + idx * 1024;
    *reinterpret_cast<float4*>(&sW1[q >> 6][q & 63]) = *reinterpret_cast<const float4*>(W1 + q);
  }
#pragma unroll
  for (int idx = 0; idx < 2; ++idx) {
    int q = t * 4 + idx * 1024;
    *reinterpret_cast<float4*>(&sW2[q >> 6][q & 63]) = *reinterpret_cast<const float4*>(Ws2 + q);
    int r = q >> 5, kk = q & 31;
    float4 v = *reinterpret_cast<const float4*>(rf + (size_t)(n0 + r) * 32 + kk);
    sRF[kk][r] = v.x; sRF[kk + 1][r] = v.y; sRF[kk + 2][r] = v.z; sRF[kk + 3][r] = v.w;
  }
  __syncthreads();
  int tn = (t & 15) * 4, tj = (t >> 4) * 4;
  float acc[4][4] = {};
#pragma unroll 8
  for (int k = 0; k < 32; ++k) {
    float4 a = *reinterpret_cast<const float4*>(&sRF[k][tn]);
    float4 b = *reinterpret_cast<const float4*>(&sW2[k][tj]);
    acc[0][0] = fmaf(a.x, b.x, acc[0][0]); acc[0][1] = fmaf(a.x, b.y, acc[0][1]);
    acc[0][2] = fmaf(a.x, b.z, acc[0][2]); acc[0][3] = fmaf(a.x, b.w, acc[0][3]);
    acc[1][0] = fmaf(a.y, b.x, acc[1][0]); acc[1][1] = fmaf(a.y, b.y, acc[1][1]);
    acc[1][2] = fmaf(a.y, b.z, acc[1][2]); acc[1][3] = fmaf(a.y, b.w, acc[1][3]);
    acc[2][0] = fmaf(a.z, b.x, acc[2][0]); acc[2][1] = fmaf(a.z, b.y, acc[2][1]);
    acc[2][2] = fmaf(a.z, b.z, acc[2][2]); acc[2][3] = fmaf(a.z, b.w, acc[2][3]);
    acc[3][0] = fmaf(a.w, b.x, acc[3][0]); acc[3][1] = fmaf(a.w, b.y, acc[3][1]);
    acc[3][2] = fmaf(a.w, b.z, acc[3][2]); acc[3][3] = fmaf(a.w, b.w, acc[3][3]);
  }
  float4 bg = *reinterpret_cast<const float4*>(g2b + tj);
  float4 z4 = make_float4(0.f, 0.f, 0.f, 0.f);
#pragma unroll
  for (int i = 0; i < 4; ++i) {
    int n = n0 + tn + i;
    float4 g = *reinterpret_cast<const float4*>(&agg[(size_t)n * 64 + tj]);
    *reinterpret_cast<float4*>(&agg[(size_t)n * 64 + tj]) = z4;  // re-arm for next iter
    sO[tj + 0][tn + i] = fmaxf(acc[i][0] + g.x + bg.x, 0.f);
    sO[tj + 1][tn + i] = fmaxf(acc[i][1] + g.y + bg.y, 0.f);
    sO[tj + 2][tn + i] = fmaxf(acc[i][2] + g.z + bg.z, 0.f);
    sO[tj + 3][tn + i] = fmaxf(acc[i][3] + g.w + bg.w, 0.f);
  }
  __syncthreads();
  float acc2[4][4] = {};
#pragma unroll 8
  for (int k = 0; k < 64; ++k) {
    float4 a = *reinterpret_cast<const float4*>(&sO[k][tn]);
    float4 b = *reinterpret_cast<const float4*>(&sW1[k][tj]);
    acc2[0][0] = fmaf(a.x, b.x, acc2[0][0]); acc2[0][1] = fmaf(a.x, b.y, acc2[0][1]);
    acc2[0][2] = fmaf(a.x, b.z, acc2[0][2]); acc2[0][3] = fmaf(a.x, b.w, acc2[0][3]);
    acc2[1][0] = fmaf(a.y, b.x, acc2[1][0]); acc2[1][1] = fmaf(a.y, b.y, acc2[1][1]);
    acc2[1][2] = fmaf(a.y, b.z, acc2[1][2]); acc2[1][3] = fmaf(a.y, b.w, acc2[1][3]);
    acc2[2][0] = fmaf(a.z, b.x, acc2[2][0]); acc2[2][1] = fmaf(a.z, b.y, acc2[2][1]);
    acc2[2][2] = fmaf(a.z, b.z, acc2[2][2]); acc2[2][3] = fmaf(a.z, b.w, acc2[2][3]);
    acc2[3][0] = fmaf(a.w, b.x, acc2[3][0]); acc2[3][1] = fmaf(a.w, b.y, acc2[3][1]);
    acc2[3][2] = fmaf(a.w, b.z, acc2[3][2]); acc2[3][3] = fmaf(a.w, b.w, acc2[3][3]);
  }
  float4 b1v = make_float4(0.f, 0.f, 0.f, 0.f);
  if (!isP) b1v = *reinterpret_cast<const float4*>(b1 + tj);
#pragma unroll
  for (int i = 0; i < 4; ++i) {
    int n = n0 + tn + i;
    float4 o;
    o.x = acc2[i][0] + b1v.x; o.y = acc2[i][1] + b1v.y;
    o.z = acc2[i][2] + b1v.z; o.w = acc2[i][3] + b1v.w;
    *reinterpret_cast<float4*>(&u[(size_t)n * 64 + tj]) = o;
  }
}

// ====== upd_soft: Mhat += pairwise MLP; fused row softmax -> (Msoft | final out);
//        optional RNG for next iteration. 512 blocks. ======
__global__ __launch_bounds__(256) void upd_soft(
    const float* __restrict__ uR, const float* __restrict__ uP,
    const float* __restrict__ W2, const float* __restrict__ b2p,
    float* __restrict__ Mhat, float* __restrict__ softDst,
    int writeMhat, float* __restrict__ rfr, int doRng,
    unsigned fk0, unsigned fk1) {
  __shared__ float sur[16][66];
  __shared__ float sup[128][66];
  __shared__ float sw2[64];
  int gid = blockIdx.x, t = threadIdx.x;
  int b = gid >> 3, r0 = (gid & 7) * 16;
  const float* urG = uR + ((size_t)(b * 128 + r0)) * 64;
  {
    int q = t * 4; int r = q >> 6, d = q & 63;
    float4 v = *reinterpret_cast<const float4*>(urG + q);
    sur[r][d] = v.x; sur[r][d + 1] = v.y; sur[r][d + 2] = v.z; sur[r][d + 3] = v.w;
  }
  const float* upG = uP + (size_t)b * 128 * 64;
#pragma unroll
  for (int rep = 0; rep < 8; ++rep) {
    int q = (rep * 256 + t) * 4; int p = q >> 6, d = q & 63;
    float4 v = *reinterpret_cast<const float4*>(upG + q);
    sup[p][d] = v.x; sup[p][d + 1] = v.y; sup[p][d + 2] = v.z; sup[p][d + 3] = v.w;
  }
  if (t < 64) sw2[t] = W2[t];
  __syncthreads();
  int tx = t & 31, ty = t >> 5;
  float acc[2][4] = {};
  for (int j = 0; j < 64; ++j) {
    float w2v = sw2[j];
    float a0 = sur[ty][j], a1 = sur[ty + 8][j];
    float q0 = sup[tx][j], q1 = sup[tx + 32][j], q2 = sup[tx + 64][j], q3 = sup[tx + 96][j];
    acc[0][0] = fmaf(fmaxf(a0 - q0, 0.f), w2v, acc[0][0]);
    acc[0][1] = fmaf(fmaxf(a0 - q1, 0.f), w2v, acc[0][1]);
    acc[0][2] = fmaf(fmaxf(a0 - q2, 0.f), w2v, acc[0][2]);
    acc[0][3] = fmaf(fmaxf(a0 - q3, 0.f), w2v, acc[0][3]);
    acc[1][0] = fmaf(fmaxf(a1 - q0, 0.f), w2v, acc[1][0]);
    acc[1][1] = fmaf(fmaxf(a1 - q1, 0.f), w2v, acc[1][1]);
    acc[1][2] = fmaf(fmaxf(a1 - q2, 0.f), w2v, acc[1][2]);
    acc[1][3] = fmaf(fmaxf(a1 - q3, 0.f), w2v, acc[1][3]);
  }
  float b2v = b2p[0];
#pragma unroll
  for (int ii = 0; ii < 2; ++ii) {
    int r = r0 + ty + 8 * ii;
    float* mrow = Mhat + ((size_t)(b * 128 + r)) * 128;
    float m0 = mrow[tx] + acc[ii][0] + b2v;
    float m1 = mrow[tx + 32] + acc[ii][1] + b2v;
    float m2 = mrow[tx + 64] + acc[ii][2] + b2v;
    float m3 = mrow[tx + 96] + acc[ii][3] + b2v;
    if (writeMhat) {
      mrow[tx] = m0; mrow[tx + 32] = m1; mrow[tx + 64] = m2; mrow[tx + 96] = m3;
    }
    float mx = redmax32(fmaxf(fmaxf(m0, m1), fmaxf(m2, m3)));
    float e0 = __expf(m0 - mx), e1 = __expf(m1 - mx);
    float e2 = __expf(m2 - mx), e3 = __expf(m3 - mx);
    float inv = 1.0f / redsum32(e0 + e1 + e2 + e3);
    float* srow = softDst + ((size_t)(b * 128 + r)) * 128;
    srow[tx] = e0 * inv; srow[tx + 32] = e1 * inv;
    srow[tx + 64] = e2 * inv; srow[tx + 96] = e3 * inv;
  }
  if (doRng) {
    int gtid = (gid << 8) + t;
#pragma unroll
    for (int q = 0; q < 2; ++q) {
      unsigned i = (unsigned)gtid + (unsigned)q * 131072u;
      unsigned a0 = 0u, a1 = i;
      tf2x32(fk0, fk1, a0, a1);
      rfr[i] = bits_to_normal(a0 ^ a1);
    }
  }
}

extern "C" void kernel_launch(void* const* d_in, const int* in_sizes, int n_in,
                              void* d_out, int out_size, void* d_ws, size_t ws_size,
                              hipStream_t stream) {
  (void)in_sizes; (void)n_in; (void)out_size; (void)ws_size;
  const float* x_r  = (const float*)d_in[0];
  const int*   ei_r = (const int*)d_in[1];
  const float* ef_r = (const float*)d_in[2];
  const float* x_p  = (const float*)d_in[3];
  const int*   ei_p = (const int*)d_in[4];
  const float* ef_p = (const float*)d_in[5];
  const float* g1_Ws = (const float*)d_in[8];
  const float* g1_Wm = (const float*)d_in[9];
  const float* g1_We = (const float*)d_in[10];
  const float* g1_b  = (const float*)d_in[11];
  const float* g2_Ws = (const float*)d_in[12];
  const float* g2_Wm = (const float*)d_in[13];
  const float* g2_We = (const float*)d_in[14];
  const float* g2_b  = (const float*)d_in[15];
  const float* W1 = (const float*)d_in[16];
  const float* b1 = (const float*)d_in[17];
  const float* W2 = (const float*)d_in[18];
  const float* b2 = (const float*)d_in[19];
  float* out = (float*)d_out;

  float* ws = (float*)d_ws;
  float* h_r   = ws;                 // 524288
  float* h_p   = h_r + 524288;       // 524288
  float* Mhat  = h_p + 524288;       // 1048576
  float* Msoft = Mhat + 1048576;     // 1048576
  float* rfr   = Msoft + 1048576;    // 262144
  float* rfp   = rfr + 262144;       // 262144
  float* u_r   = rfp + 262144;       // 524288
  float* u_p   = u_r + 524288;       // 524288
  float* agg_r = u_p + 524288;       // 524288
  float* agg_p = agg_r + 524288;     // 524288 (contiguous for zeroing)
  int* ib      = (int*)(agg_p + 524288);
  int* off_r  = ib;                  // 8192 (zeroed)
  int* off_p  = off_r + 8192;        // 8192
  int* perm_r = off_p + 8192;        // 65536
  int* perm_p = perm_r + 65536;      // 65536
  int* srcs_r = perm_p + 65536;      // 65536
  int* srcs_p = srcs_r + 65536;      // 65536
  int* dsts_r = srcs_p + 65536;      // 65536
  int* dsts_p = dsts_r + 65536;      // 65536

  unsigned fk0[3], fk1[3];
  for (int it = 0; it < 3; ++it) {
    unsigned a = 0u, c = (unsigned)it;
    tf2x32(0u, 42u, a, c);
    fk0[it] = a; fk1[it] = c;
  }

  // ---- CSR build + agg zeroing ----
  hipMemsetAsync(off_r, 0, 2 * 8192 * sizeof(int), stream);
  hist_kern<<<512, 256, 0, stream>>>(ei_r, ei_p, off_r, off_p, agg_r);
  scan_kern<<<2, 256, 0, stream>>>(off_r, off_p);
  scatter_kern<<<512, 256, 0, stream>>>(ei_r, ei_p, off_r, off_p,
                                        perm_r, perm_p, srcs_r, srcs_p,
                                        dsts_r, dsts_p);

  // ---- gnn1 ----
  msg_gemm<64><<<2048, 256, 0, stream>>>(x_r, ef_r, srcs_r, perm_r, dsts_r, agg_r,
                                         x_p, ef_p, srcs_p, perm_p, dsts_p, agg_p,
                                         g1_Wm, g1_We);
  node1_gemm<<<256, 256, 0, stream>>>(x_r, agg_r, h_r, x_p, agg_p, h_p, g1_Ws, g1_b);
  mhat_soft<<<512, 256, 0, stream>>>(h_r, h_p, Mhat, Msoft, out, rfr, fk0[0], fk1[0]);

  for (int it = 0; it < 3; ++it) {
    rfp_kern<<<512, 256, 0, stream>>>(Msoft, rfr, rfp);
    msg_gemm<32><<<2048, 256, 0, stream>>>(rfr, ef_r, srcs_r, perm_r, dsts_r, agg_r,
                                           rfp, ef_p, srcs_p, perm_p, dsts_p, agg_p,
                                           g2_Wm, g2_We);
    node2u_gemm<<<256, 256, 0, stream>>>(rfr, agg_r, u_r, rfp, agg_p, u_p,
                                         g2_Ws, g2_b, W1, b1);
    int last = (it == 2);
    upd_soft<<<512, 256, 0, stream>>>(u_r, u_p, W2, b2, Mhat,
                                      last ? (out + 1048576) : Msoft,
                                      /*writeMhat=*/!last,
                                      rfr, /*doRng=*/!last,
                                      fk0[it < 2 ? it + 1 : 0], fk1[it < 2 ? it + 1 : 0]);
  }
}

// Round 15
// 299.043 us; speedup vs baseline: 2.1052x; 1.0452x over previous
//
#include <hip/hip_runtime.h>

// Problem constants
constexpr int kE = 65536, kNTOT = 8192;

// ---------------- threefry2x32 (JAX-exact, 20 rounds) ----------------
__host__ __device__ __forceinline__ void tf_round(unsigned& x0, unsigned& x1, int r) {
  x0 += x1;
  x1 = (x1 << r) | (x1 >> (32 - r));
  x1 ^= x0;
}
__host__ __device__ __forceinline__ void tf2x32(unsigned k0, unsigned k1,
                                                unsigned& x0, unsigned& x1) {
  unsigned ks2 = k0 ^ k1 ^ 0x1BD11BDAu;
  x0 += k0; x1 += k1;
  tf_round(x0,x1,13); tf_round(x0,x1,15); tf_round(x0,x1,26); tf_round(x0,x1,6);
  x0 += k1; x1 += ks2 + 1u;
  tf_round(x0,x1,17); tf_round(x0,x1,29); tf_round(x0,x1,16); tf_round(x0,x1,24);
  x0 += ks2; x1 += k0 + 2u;
  tf_round(x0,x1,13); tf_round(x0,x1,15); tf_round(x0,x1,26); tf_round(x0,x1,6);
  x0 += k0; x1 += k1 + 3u;
  tf_round(x0,x1,17); tf_round(x0,x1,29); tf_round(x0,x1,16); tf_round(x0,x1,24);
  x0 += k1; x1 += ks2 + 4u;
  tf_round(x0,x1,13); tf_round(x0,x1,15); tf_round(x0,x1,26); tf_round(x0,x1,6);
  x0 += ks2; x1 += k0 + 5u;
}

// bits -> N(0,1), replicating jax.random.normal f32 path (partitionable threefry)
__device__ __forceinline__ float bits_to_normal(unsigned bits) {
  float f = __uint_as_float((bits >> 9) | 0x3f800000u) - 1.0f;  // [0,1)
  const float LO = -0.99999994f;
  float u = fmaf(f, 2.0f, LO);
  u = fmaxf(u, LO);
  float w = -log1pf(-u * u);
  float p;
  if (w < 5.0f) {
    w -= 2.5f;
    p = 2.81022636e-08f;
    p = fmaf(p, w, 3.43273939e-07f);
    p = fmaf(p, w, -3.5233877e-06f);
    p = fmaf(p, w, -4.39150654e-06f);
    p = fmaf(p, w, 0.00021858087f);
    p = fmaf(p, w, -0.00125372503f);
    p = fmaf(p, w, -0.00417768164f);
    p = fmaf(p, w, 0.246640727f);
    p = fmaf(p, w, 1.50140941f);
  } else {
    w = sqrtf(w) - 3.0f;
    p = -0.000200214257f;
    p = fmaf(p, w, 0.000100950558f);
    p = fmaf(p, w, 0.00134934322f);
    p = fmaf(p, w, -0.00367342844f);
    p = fmaf(p, w, 0.00573950773f);
    p = fmaf(p, w, -0.0076224613f);
    p = fmaf(p, w, 0.00943887047f);
    p = fmaf(p, w, 1.00167406f);
    p = fmaf(p, w, 2.83297682f);
  }
  return 1.41421356f * (p * u);
}

__device__ __forceinline__ float redmax32(float v) {
#pragma unroll
  for (int o = 16; o > 0; o >>= 1) v = fmaxf(v, __shfl_xor(v, o));
  return v;
}
__device__ __forceinline__ float redsum32(float v) {
#pragma unroll
  for (int o = 16; o > 0; o >>= 1) v += __shfl_xor(v, o);
  return v;
}

// ================= CSR build (multi-block) + agg zeroing =================
__global__ __launch_bounds__(256) void hist_kern(const int* __restrict__ eiR,
                                                 const int* __restrict__ eiP,
                                                 int* __restrict__ offR,
                                                 int* __restrict__ offP,
                                                 float* __restrict__ aggz) {
  int i = blockIdx.x * 256 + threadIdx.x;  // 0..131071
  float4 z4 = make_float4(0.f, 0.f, 0.f, 0.f);
  float4* z = reinterpret_cast<float4*>(aggz) + i * 2;
  z[0] = z4; z[1] = z4;
  const int* ei = (i < kE) ? eiR : eiP;
  int* off = (i < kE) ? offR : offP;
  int e = i & (kE - 1);
  atomicAdd(&off[ei[kE + e]], 1);
}

// 2 blocks (one per graph): in-place exclusive scan of off[] (counts -> offsets)
__global__ __launch_bounds__(256) void scan_kern(int* __restrict__ offR,
                                                 int* __restrict__ offP) {
  int* off = blockIdx.x ? offP : offR;
  int t = threadIdx.x;
  int base = t * 32;
  int v[32];
#pragma unroll
  for (int i = 0; i < 32; ++i) v[i] = off[base + i];
  int sum = 0;
#pragma unroll
  for (int i = 0; i < 32; ++i) sum += v[i];
  int lane = t & 63, w = t >> 6;
  int incl = sum;
#pragma unroll
  for (int o = 1; o < 64; o <<= 1) {
    int y = __shfl_up(incl, o);
    if (lane >= o) incl += y;
  }
  __shared__ int wsum[4];
  if (lane == 63) wsum[w] = incl;
  __syncthreads();
  int woff = 0;
#pragma unroll
  for (int i = 0; i < 4; ++i) if (i < w) woff += wsum[i];
  int running = woff + incl - sum;
#pragma unroll
  for (int i = 0; i < 32; ++i) {
    off[base + i] = running;
    running += v[i];
  }
}

__global__ __launch_bounds__(256) void scatter_kern(
    const int* __restrict__ eiR, const int* __restrict__ eiP,
    int* __restrict__ offR, int* __restrict__ offP,
    int* __restrict__ permR, int* __restrict__ permP,
    int* __restrict__ srcsR, int* __restrict__ srcsP,
    int* __restrict__ dstsR, int* __restrict__ dstsP) {
  int i = blockIdx.x * 256 + threadIdx.x;
  const int* ei = (i < kE) ? eiR : eiP;
  int* off = (i < kE) ? offR : offP;
  int* perm = (i < kE) ? permR : permP;
  int* srcs = (i < kE) ? srcsR : srcsP;
  int* dsts = (i < kE) ? dstsR : dstsP;
  int e = i & (kE - 1);
  int dst = ei[kE + e];
  int pos = atomicAdd(&off[dst], 1);
  perm[pos] = e;
  srcs[pos] = ei[e];
  dsts[pos] = dst;
}

// ====== msg GEMM + fused segment-reduce aggregation (both graphs) ======
// Staging uses a 4-lane in-register transpose so LDS writes are float4 along r
// (conflict-free) instead of scalar k-major writes (10-way conflicts at stride 68).
template <int KX>
__global__ __launch_bounds__(256) void msg_gemm(
    const float* __restrict__ xR, const float* __restrict__ efR,
    const int* __restrict__ srcsR, const int* __restrict__ permR,
    const int* __restrict__ dstsR, float* __restrict__ aggR,
    const float* __restrict__ xP, const float* __restrict__ efP,
    const int* __restrict__ srcsP, const int* __restrict__ permP,
    const int* __restrict__ dstsP, float* __restrict__ aggP,
    const float* __restrict__ Wm, const float* __restrict__ We) {
  constexpr int KT = KX + 16;
  constexpr int SA_ROWS = (KT > 64) ? KT : 64;
  __shared__ float sA[SA_ROWS][68];
  __shared__ float sW[KT][68];
  __shared__ int sDst[64];
  __shared__ int sSrc[64];
  __shared__ int sPerm[64];
  bool isP = blockIdx.x >= 1024;
  const float* x = isP ? xP : xR;
  const float* ef = isP ? efP : efR;
  const int* srcs = isP ? srcsP : srcsR;
  const int* perm = isP ? permP : permR;
  const int* dsts = isP ? dstsP : dstsR;
  float* agg = isP ? aggP : aggR;
  int i0 = (blockIdx.x & 1023) * 64;
  int t = threadIdx.x;
#pragma unroll
  for (int idx = 0; idx < KT * 64 / 1024; ++idx) {
    int q = t * 4 + idx * 1024;
    int k = q >> 6, j = q & 63;
    const float* sp = (k < KX) ? (Wm + k * 64 + j) : (We + (k - KX) * 64 + j);
    float4 v = *reinterpret_cast<const float4*>(sp);
    *reinterpret_cast<float4*>(&sW[k][j]) = v;
  }
  if (t < 64) {
    sDst[t] = dsts[i0 + t];
    sSrc[t] = srcs[i0 + t];
    sPerm[t] = perm[i0 + t];
  }
  __syncthreads();
  // staging: per 16-k slab, group of 4 lanes <-> 4 edges at one k-quad
  {
    int l = t & 3;
    int g = t >> 2;            // 0..63
    int rb = g >> 2;           // r-block of 4 (0..15)
    int kq = g & 3;            // k-quad within slab (0..3)
    int gbase = (t & 63) & ~3; // group base lane within wave
#pragma unroll
    for (int idx = 0; idx < KT / 16; ++idx) {
      int k4 = idx * 16 + kq * 4;
      int r = rb * 4 + l;
      const float* rptr = (k4 < KX) ? (x + (size_t)sSrc[r] * KX + k4)
                                    : (ef + (size_t)sPerm[r] * 16 + (k4 - KX));
      float4 v = *reinterpret_cast<const float4*>(rptr);
      float vc[4] = {v.x, v.y, v.z, v.w};
      float out[4];
#pragma unroll
      for (int c = 0; c < 4; ++c) {
        float val = vc[(l - c) & 3];               // provide component (s-c)&3
        out[(l + c) & 3] = __shfl(val, gbase + ((l + c) & 3), 64);
      }
      // lane l now holds out[j] = A[r=rb*4+j][k4+l]; float4 write along r
      *reinterpret_cast<float4*>(&sA[k4 + l][rb * 4]) =
          make_float4(out[0], out[1], out[2], out[3]);
    }
  }
  __syncthreads();
  int tn = (t & 15) * 4;
  int tj = (t >> 4) * 4;
  float acc[4][4] = {};
#pragma unroll 8
  for (int k = 0; k < KT; ++k) {
    float4 a = *reinterpret_cast<const float4*>(&sA[k][tn]);
    float4 b = *reinterpret_cast<const float4*>(&sW[k][tj]);
    acc[0][0] = fmaf(a.x, b.x, acc[0][0]); acc[0][1] = fmaf(a.x, b.y, acc[0][1]);
    acc[0][2] = fmaf(a.x, b.z, acc[0][2]); acc[0][3] = fmaf(a.x, b.w, acc[0][3]);
    acc[1][0] = fmaf(a.y, b.x, acc[1][0]); acc[1][1] = fmaf(a.y, b.y, acc[1][1]);
    acc[1][2] = fmaf(a.y, b.z, acc[1][2]); acc[1][3] = fmaf(a.y, b.w, acc[1][3]);
    acc[2][0] = fmaf(a.z, b.x, acc[2][0]); acc[2][1] = fmaf(a.z, b.y, acc[2][1]);
    acc[2][2] = fmaf(a.z, b.z, acc[2][2]); acc[2][3] = fmaf(a.z, b.w, acc[2][3]);
    acc[3][0] = fmaf(a.w, b.x, acc[3][0]); acc[3][1] = fmaf(a.w, b.y, acc[3][1]);
    acc[3][2] = fmaf(a.w, b.z, acc[3][2]); acc[3][3] = fmaf(a.w, b.w, acc[3][3]);
  }
  __syncthreads();            // reuse sA as output tile [row][col]; float4 stores
#pragma unroll
  for (int i = 0; i < 4; ++i) {
    *reinterpret_cast<float4*>(&sA[tn + i][tj]) =
        make_float4(fmaxf(acc[i][0], 0.f), fmaxf(acc[i][1], 0.f),
                    fmaxf(acc[i][2], 0.f), fmaxf(acc[i][3], 0.f));
  }
  __syncthreads();
  // segment-reduce: 64 cols x 4 row-chunks of 16; one atomic per dst-run per col
  int col = t & 63;
  int r0l = (t >> 6) * 16;
  float run = 0.f;
  int rd = sDst[r0l];
#pragma unroll
  for (int r = 0; r < 16; ++r) {
    int d = sDst[r0l + r];
    if (d != rd) {
      unsafeAtomicAdd(&agg[(size_t)rd * 64 + col], run);
      run = 0.f; rd = d;
    }
    run += sA[r0l + r][col];
  }
  unsafeAtomicAdd(&agg[(size_t)rd * 64 + col], run);
}

// ====== node1 dense tiled GEMM: h = relu(X@Ws + agg + b); re-zeroes agg ======
__global__ __launch_bounds__(256) void node1_gemm(
    const float* __restrict__ xR, float* __restrict__ aggR, float* __restrict__ hR,
    const float* __restrict__ xP, float* __restrict__ aggP, float* __restrict__ hP,
    const float* __restrict__ Ws, const float* __restrict__ bias) {
  __shared__ float sX[64][68];
  __shared__ float sW[64][68];
  bool isP = blockIdx.x >= 128;
  const float* x = isP ? xP : xR;
  float* agg = isP ? aggP : aggR;
  float* h = isP ? hP : hR;
  int n0 = (blockIdx.x & 127) * 64;
  int t = threadIdx.x;
#pragma unroll
  for (int idx = 0; idx < 4; ++idx) {
    int q = t * 4 + idx * 1024;
    int k = q >> 6, j = q & 63;
    *reinterpret_cast<float4*>(&sW[k][j]) = *reinterpret_cast<const float4*>(Ws + q);
    float4 v = *reinterpret_cast<const float4*>(x + (size_t)n0 * 64 + q);
    sX[j + 0][k] = v.x; sX[j + 1][k] = v.y; sX[j + 2][k] = v.z; sX[j + 3][k] = v.w;
  }
  __syncthreads();
  int tn = (t & 15) * 4, tj = (t >> 4) * 4;
  float acc[4][4] = {};
#pragma unroll 8
  for (int k = 0; k < 64; ++k) {
    float4 a = *reinterpret_cast<const float4*>(&sX[k][tn]);
    float4 b = *reinterpret_cast<const float4*>(&sW[k][tj]);
    acc[0][0] = fmaf(a.x, b.x, acc[0][0]); acc[0][1] = fmaf(a.x, b.y, acc[0][1]);
    acc[0][2] = fmaf(a.x, b.z, acc[0][2]); acc[0][3] = fmaf(a.x, b.w, acc[0][3]);
    acc[1][0] = fmaf(a.y, b.x, acc[1][0]); acc[1][1] = fmaf(a.y, b.y, acc[1][1]);
    acc[1][2] = fmaf(a.y, b.z, acc[1][2]); acc[1][3] = fmaf(a.y, b.w, acc[1][3]);
    acc[2][0] = fmaf(a.z, b.x, acc[2][0]); acc[2][1] = fmaf(a.z, b.y, acc[2][1]);
    acc[2][2] = fmaf(a.z, b.z, acc[2][2]); acc[2][3] = fmaf(a.z, b.w, acc[2][3]);
    acc[3][0] = fmaf(a.w, b.x, acc[3][0]); acc[3][1] = fmaf(a.w, b.y, acc[3][1]);
    acc[3][2] = fmaf(a.w, b.z, acc[3][2]); acc[3][3] = fmaf(a.w, b.w, acc[3][3]);
  }
  float4 bv = *reinterpret_cast<const float4*>(bias + tj);
  float4 z4 = make_float4(0.f, 0.f, 0.f, 0.f);
#pragma unroll
  for (int i = 0; i < 4; ++i) {
    int n = n0 + tn + i;
    float4 g = *reinterpret_cast<const float4*>(&agg[(size_t)n * 64 + tj]);
    *reinterpret_cast<float4*>(&agg[(size_t)n * 64 + tj]) = z4;  // re-arm for next iter
    float4 o;
    o.x = fmaxf(acc[i][0] + g.x + bv.x, 0.f);
    o.y = fmaxf(acc[i][1] + g.y + bv.y, 0.f);
    o.z = fmaxf(acc[i][2] + g.z + bv.z, 0.f);
    o.w = fmaxf(acc[i][3] + g.w + bv.w, 0.f);
    *reinterpret_cast<float4*>(&h[(size_t)n * 64 + tj]) = o;
  }
}

// ====== mhat_soft: Mhat tile + fused row softmax (->Msoft, ->out M0) + it0 RNG ======
__global__ __launch_bounds__(256) void mhat_soft(
    const float* __restrict__ hR, const float* __restrict__ hP,
    float* __restrict__ Mhat, float* __restrict__ Msoft, float* __restrict__ M0out,
    float* __restrict__ rfr, unsigned fk0, unsigned fk1) {
  __shared__ float hr[16][66];
  __shared__ float hp[128][66];
  int gid = blockIdx.x, t = threadIdx.x;
  int gtid = (gid << 8) + t;
#pragma unroll
  for (int q = 0; q < 2; ++q) {
    unsigned i = (unsigned)gtid + (unsigned)q * 131072u;
    unsigned a0 = 0u, a1 = i;
    tf2x32(fk0, fk1, a0, a1);
    rfr[i] = bits_to_normal(a0 ^ a1);
  }
  int b = gid >> 3, r0 = (gid & 7) * 16;
  const float* hrG = hR + ((size_t)(b * 128 + r0)) * 64;
  {
    int q = t * 4; int r = q >> 6, d = q & 63;
    float4 v = *reinterpret_cast<const float4*>(hrG + q);
    hr[r][d] = v.x; hr[r][d + 1] = v.y; hr[r][d + 2] = v.z; hr[r][d + 3] = v.w;
  }
  const float* hpG = hP + (size_t)b * 128 * 64;
#pragma unroll
  for (int rep = 0; rep < 8; ++rep) {
    int q = (rep * 256 + t) * 4; int p = q >> 6, d = q & 63;
    float4 v = *reinterpret_cast<const float4*>(hpG + q);
    hp[p][d] = v.x; hp[p][d + 1] = v.y; hp[p][d + 2] = v.z; hp[p][d + 3] = v.w;
  }
  __syncthreads();
  int tx = t & 31, ty = t >> 5;
  float acc[2][4] = {};
  for (int d = 0; d < 64; ++d) {
    float a0 = hr[ty][d], a1 = hr[ty + 8][d];
    float q0 = hp[tx][d], q1 = hp[tx + 32][d], q2 = hp[tx + 64][d], q3 = hp[tx + 96][d];
    acc[0][0] = fmaf(a0, q0, acc[0][0]); acc[0][1] = fmaf(a0, q1, acc[0][1]);
    acc[0][2] = fmaf(a0, q2, acc[0][2]); acc[0][3] = fmaf(a0, q3, acc[0][3]);
    acc[1][0] = fmaf(a1, q0, acc[1][0]); acc[1][1] = fmaf(a1, q1, acc[1][1]);
    acc[1][2] = fmaf(a1, q2, acc[1][2]); acc[1][3] = fmaf(a1, q3, acc[1][3]);
  }
#pragma unroll
  for (int ii = 0; ii < 2; ++ii) {
    int r = r0 + ty + 8 * ii;
    float* mrow = Mhat + ((size_t)(b * 128 + r)) * 128;
    mrow[tx] = acc[ii][0]; mrow[tx + 32] = acc[ii][1];
    mrow[tx + 64] = acc[ii][2]; mrow[tx + 96] = acc[ii][3];
    float mx = redmax32(fmaxf(fmaxf(acc[ii][0], acc[ii][1]), fmaxf(acc[ii][2], acc[ii][3])));
    float e0 = __expf(acc[ii][0] - mx), e1 = __expf(acc[ii][1] - mx);
    float e2 = __expf(acc[ii][2] - mx), e3 = __expf(acc[ii][3] - mx);
    float inv = 1.0f / redsum32(e0 + e1 + e2 + e3);
    float* srow = Msoft + ((size_t)(b * 128 + r)) * 128;
    srow[tx] = e0 * inv; srow[tx + 32] = e1 * inv;
    srow[tx + 64] = e2 * inv; srow[tx + 96] = e3 * inv;
    float* orow = M0out + ((size_t)(b * 128 + r)) * 128;
    orow[tx] = e0 * inv; orow[tx + 32] = e1 * inv;
    orow[tx + 64] = e2 * inv; orow[tx + 96] = e3 * inv;
  }
}

// ====== rfp: rfp[b,p,i] = sum_r Msoft[b,r,p] * rfr[b,r,i]  (512 blocks) ======
__global__ __launch_bounds__(256) void rfp_kern(
    const float* __restrict__ Msoft, const float* __restrict__ rfr,
    float* __restrict__ rfp) {
  __shared__ float rr[128][36];
  int b = blockIdx.x >> 3, p0 = (blockIdx.x & 7) * 16;
  int t = threadIdx.x;
  const float* rfG = rfr + (size_t)b * 4096;
#pragma unroll
  for (int rep = 0; rep < 4; ++rep) {
    int q = (rep * 256 + t) * 4; int r = q >> 5, i = q & 31;
    float4 v = *reinterpret_cast<const float4*>(rfG + q);
    rr[r][i] = v.x; rr[r][i + 1] = v.y; rr[r][i + 2] = v.z; rr[r][i + 3] = v.w;
  }
  __syncthreads();
  int pl = t & 15, ih = (t >> 4) * 2;
  int p = p0 + pl;
  const float* Mcol = Msoft + (size_t)b * 16384 + p;
  float a0 = 0.f, a1 = 0.f;
#pragma unroll 8
  for (int r = 0; r < 128; ++r) {
    float m = Mcol[(size_t)r * 128];
    a0 = fmaf(m, rr[r][ih], a0);
    a1 = fmaf(m, rr[r][ih + 1], a1);
  }
  float* dst = rfp + ((size_t)(b * 128 + p)) * 32 + ih;
  dst[0] = a0; dst[1] = a1;
}

// ====== node2u: o = relu(rf@Ws2 + agg + g2b); u = o@W1 (+b1); re-zeroes agg ======
__global__ __launch_bounds__(256) void node2u_gemm(
    const float* __restrict__ rfR, float* __restrict__ aggR, float* __restrict__ uR,
    const float* __restrict__ rfP, float* __restrict__ aggP, float* __restrict__ uP,
    const float* __restrict__ Ws2, const float* __restrict__ g2b,
    const float* __restrict__ W1, const float* __restrict__ b1) {
  __shared__ float sRF[32][68];
  __shared__ float sW2[32][68];
  __shared__ float sW1[64][68];
  __shared__ float sO[64][68];
  bool isP = blockIdx.x >= 128;
  const float* rf = isP ? rfP : rfR;
  float* agg = isP ? aggP : aggR;
  float* u = isP ? uP : uR;
  int n0 = (blockIdx.x & 127) * 64;
  int t = threadIdx.x;
#pragma unroll
  for (int idx = 0; idx < 4; ++idx) {
    int q = t * 4 + idx * 1024;
    *reinterpret_cast<float4*>(&sW1[q >> 6][q & 63]) = *reinterpret_cast<const float4*>(W1 + q);
  }
#pragma unroll
  for (int idx = 0; idx < 2; ++idx) {
    int q = t * 4 + idx * 1024;
    *reinterpret_cast<float4*>(&sW2[q >> 6][q & 63]) = *reinterpret_cast<const float4*>(Ws2 + q);
    int r = q >> 5, kk = q & 31;
    float4 v = *reinterpret_cast<const float4*>(rf + (size_t)(n0 + r) * 32 + kk);
    sRF[kk][r] = v.x; sRF[kk + 1][r] = v.y; sRF[kk + 2][r] = v.z; sRF[kk + 3][r] = v.w;
  }
  __syncthreads();
  int tn = (t & 15) * 4, tj = (t >> 4) * 4;
  float acc[4][4] = {};
#pragma unroll 8
  for (int k = 0; k < 32; ++k) {
    float4 a = *reinterpret_cast<const float4*>(&sRF[k][tn]);
    float4 b = *reinterpret_cast<const float4*>(&sW2[k][tj]);
    acc[0][0] = fmaf(a.x, b.x, acc[0][0]); acc[0][1] = fmaf(a.x, b.y, acc[0][1]);
    acc[0][2] = fmaf(a.x, b.z, acc[0][2]); acc[0][3] = fmaf(a.x, b.w, acc[0][3]);
    acc[1][0] = fmaf(a.y, b.x, acc[1][0]); acc[1][1] = fmaf(a.y, b.y, acc[1][1]);
    acc[1][2] = fmaf(a.y, b.z, acc[1][2]); acc[1][3] = fmaf(a.y, b.w, acc[1][3]);
    acc[2][0] = fmaf(a.z, b.x, acc[2][0]); acc[2][1] = fmaf(a.z, b.y, acc[2][1]);
    acc[2][2] = fmaf(a.z, b.z, acc[2][2]); acc[2][3] = fmaf(a.z, b.w, acc[2][3]);
    acc[3][0] = fmaf(a.w, b.x, acc[3][0]); acc[3][1] = fmaf(a.w, b.y, acc[3][1]);
    acc[3][2] = fmaf(a.w, b.z, acc[3][2]); acc[3][3] = fmaf(a.w, b.w, acc[3][3]);
  }
  float4 bg = *reinterpret_cast<const float4*>(g2b + tj);
  float4 z4 = make_float4(0.f, 0.f, 0.f, 0.f);
#pragma unroll
  for (int i = 0; i < 4; ++i) {
    int n = n0 + tn + i;
    float4 g = *reinterpret_cast<const float4*>(&agg[(size_t)n * 64 + tj]);
    *reinterpret_cast<float4*>(&agg[(size_t)n * 64 + tj]) = z4;  // re-arm for next iter
    sO[tj + 0][tn + i] = fmaxf(acc[i][0] + g.x + bg.x, 0.f);
    sO[tj + 1][tn + i] = fmaxf(acc[i][1] + g.y + bg.y, 0.f);
    sO[tj + 2][tn + i] = fmaxf(acc[i][2] + g.z + bg.z, 0.f);
    sO[tj + 3][tn + i] = fmaxf(acc[i][3] + g.w + bg.w, 0.f);
  }
  __syncthreads();
  float acc2[4][4] = {};
#pragma unroll 8
  for (int k = 0; k < 64; ++k) {
    float4 a = *reinterpret_cast<const float4*>(&sO[k][tn]);
    float4 b = *reinterpret_cast<const float4*>(&sW1[k][tj]);
    acc2[0][0] = fmaf(a.x, b.x, acc2[0][0]); acc2[0][1] = fmaf(a.x, b.y, acc2[0][1]);
    acc2[0][2] = fmaf(a.x, b.z, acc2[0][2]); acc2[0][3] = fmaf(a.x, b.w, acc2[0][3]);
    acc2[1][0] = fmaf(a.y, b.x, acc2[1][0]); acc2[1][1] = fmaf(a.y, b.y, acc2[1][1]);
    acc2[1][2] = fmaf(a.y, b.z, acc2[1][2]); acc2[1][3] = fmaf(a.y, b.w, acc2[1][3]);
    acc2[2][0] = fmaf(a.z, b.x, acc2[2][0]); acc2[2][1] = fmaf(a.z, b.y, acc2[2][1]);
    acc2[2][2] = fmaf(a.z, b.z, acc2[2][2]); acc2[2][3] = fmaf(a.z, b.w, acc2[2][3]);
    acc2[3][0] = fmaf(a.w, b.x, acc2[3][0]); acc2[3][1] = fmaf(a.w, b.y, acc2[3][1]);
    acc2[3][2] = fmaf(a.w, b.z, acc2[3][2]); acc2[3][3] = fmaf(a.w, b.w, acc2[3][3]);
  }
  float4 b1v = make_float4(0.f, 0.f, 0.f, 0.f);
  if (!isP) b1v = *reinterpret_cast<const float4*>(b1 + tj);
#pragma unroll
  for (int i = 0; i < 4; ++i) {
    int n = n0 + tn + i;
    float4 o;
    o.x = acc2[i][0] + b1v.x; o.y = acc2[i][1] + b1v.y;
    o.z = acc2[i][2] + b1v.z; o.w = acc2[i][3] + b1v.w;
    *reinterpret_cast<float4*>(&u[(size_t)n * 64 + tj]) = o;
  }
}

// ====== upd_soft: Mhat += pairwise MLP; fused row softmax -> (Msoft | final out);
//        optional RNG for next iteration. 512 blocks. ======
__global__ __launch_bounds__(256) void upd_soft(
    const float* __restrict__ uR, const float* __restrict__ uP,
    const float* __restrict__ W2, const float* __restrict__ b2p,
    float* __restrict__ Mhat, float* __restrict__ softDst,
    int writeMhat, float* __restrict__ rfr, int doRng,
    unsigned fk0, unsigned fk1) {
  __shared__ float sur[16][66];
  __shared__ float sup[128][66];
  __shared__ float sw2[64];
  int gid = blockIdx.x, t = threadIdx.x;
  int b = gid >> 3, r0 = (gid & 7) * 16;
  const float* urG = uR + ((size_t)(b * 128 + r0)) * 64;
  {
    int q = t * 4; int r = q >> 6, d = q & 63;
    float4 v = *reinterpret_cast<const float4*>(urG + q);
    sur[r][d] = v.x; sur[r][d + 1] = v.y; sur[r][d + 2] = v.z; sur[r][d + 3] = v.w;
  }
  const float* upG = uP + (size_t)b * 128 * 64;
#pragma unroll
  for (int rep = 0; rep < 8; ++rep) {
    int q = (rep * 256 + t) * 4; int p = q >> 6, d = q & 63;
    float4 v = *reinterpret_cast<const float4*>(upG + q);
    sup[p][d] = v.x; sup[p][d + 1] = v.y; sup[p][d + 2] = v.z; sup[p][d + 3] = v.w;
  }
  if (t < 64) sw2[t] = W2[t];
  __syncthreads();
  int tx = t & 31, ty = t >> 5;
  float acc[2][4] = {};
  for (int j = 0; j < 64; ++j) {
    float w2v = sw2[j];
    float a0 = sur[ty][j], a1 = sur[ty + 8][j];
    float q0 = sup[tx][j], q1 = sup[tx + 32][j], q2 = sup[tx + 64][j], q3 = sup[tx + 96][j];
    acc[0][0] = fmaf(fmaxf(a0 - q0, 0.f), w2v, acc[0][0]);
    acc[0][1] = fmaf(fmaxf(a0 - q1, 0.f), w2v, acc[0][1]);
    acc[0][2] = fmaf(fmaxf(a0 - q2, 0.f), w2v, acc[0][2]);
    acc[0][3] = fmaf(fmaxf(a0 - q3, 0.f), w2v, acc[0][3]);
    acc[1][0] = fmaf(fmaxf(a1 - q0, 0.f), w2v, acc[1][0]);
    acc[1][1] = fmaf(fmaxf(a1 - q1, 0.f), w2v, acc[1][1]);
    acc[1][2] = fmaf(fmaxf(a1 - q2, 0.f), w2v, acc[1][2]);
    acc[1][3] = fmaf(fmaxf(a1 - q3, 0.f), w2v, acc[1][3]);
  }
  float b2v = b2p[0];
#pragma unroll
  for (int ii = 0; ii < 2; ++ii) {
    int r = r0 + ty + 8 * ii;
    float* mrow = Mhat + ((size_t)(b * 128 + r)) * 128;
    float m0 = mrow[tx] + acc[ii][0] + b2v;
    float m1 = mrow[tx + 32] + acc[ii][1] + b2v;
    float m2 = mrow[tx + 64] + acc[ii][2] + b2v;
    float m3 = mrow[tx + 96] + acc[ii][3] + b2v;
    if (writeMhat) {
      mrow[tx] = m0; mrow[tx + 32] = m1; mrow[tx + 64] = m2; mrow[tx + 96] = m3;
    }
    float mx = redmax32(fmaxf(fmaxf(m0, m1), fmaxf(m2, m3)));
    float e0 = __expf(m0 - mx), e1 = __expf(m1 - mx);
    float e2 = __expf(m2 - mx), e3 = __expf(m3 - mx);
    float inv = 1.0f / redsum32(e0 + e1 + e2 + e3);
    float* srow = softDst + ((size_t)(b * 128 + r)) * 128;
    srow[tx] = e0 * inv; srow[tx + 32] = e1 * inv;
    srow[tx + 64] = e2 * inv; srow[tx + 96] = e3 * inv;
  }
  if (doRng) {
    int gtid = (gid << 8) + t;
#pragma unroll
    for (int q = 0; q < 2; ++q) {
      unsigned i = (unsigned)gtid + (unsigned)q * 131072u;
      unsigned a0 = 0u, a1 = i;
      tf2x32(fk0, fk1, a0, a1);
      rfr[i] = bits_to_normal(a0 ^ a1);
    }
  }
}

extern "C" void kernel_launch(void* const* d_in, const int* in_sizes, int n_in,
                              void* d_out, int out_size, void* d_ws, size_t ws_size,
                              hipStream_t stream) {
  (void)in_sizes; (void)n_in; (void)out_size; (void)ws_size;
  const float* x_r  = (const float*)d_in[0];
  const int*   ei_r = (const int*)d_in[1];
  const float* ef_r = (const float*)d_in[2];
  const float* x_p  = (const float*)d_in[3];
  const int*   ei_p = (const int*)d_in[4];
  const float* ef_p = (const float*)d_in[5];
  const float* g1_Ws = (const float*)d_in[8];
  const float* g1_Wm = (const float*)d_in[9];
  const float* g1_We = (const float*)d_in[10];
  const float* g1_b  = (const float*)d_in[11];
  const float* g2_Ws = (const float*)d_in[12];
  const float* g2_Wm = (const float*)d_in[13];
  const float* g2_We = (const float*)d_in[14];
  const float* g2_b  = (const float*)d_in[15];
  const float* W1 = (const float*)d_in[16];
  const float* b1 = (const float*)d_in[17];
  const float* W2 = (const float*)d_in[18];
  const float* b2 = (const float*)d_in[19];
  float* out = (float*)d_out;

  float* ws = (float*)d_ws;
  float* h_r   = ws;                 // 524288
  float* h_p   = h_r + 524288;       // 524288
  float* Mhat  = h_p + 524288;       // 1048576
  float* Msoft = Mhat + 1048576;     // 1048576
  float* rfr   = Msoft + 1048576;    // 262144
  float* rfp   = rfr + 262144;       // 262144
  float* u_r   = rfp + 262144;       // 524288
  float* u_p   = u_r + 524288;       // 524288
  float* agg_r = u_p + 524288;       // 524288
  float* agg_p = agg_r + 524288;     // 524288 (contiguous for zeroing)
  int* ib      = (int*)(agg_p + 524288);
  int* off_r  = ib;                  // 8192 (zeroed)
  int* off_p  = off_r + 8192;        // 8192
  int* perm_r = off_p + 8192;        // 65536
  int* perm_p = perm_r + 65536;      // 65536
  int* srcs_r = perm_p + 65536;      // 65536
  int* srcs_p = srcs_r + 65536;      // 65536
  int* dsts_r = srcs_p + 65536;      // 65536
  int* dsts_p = dsts_r + 65536;      // 65536

  unsigned fk0[3], fk1[3];
  for (int it = 0; it < 3; ++it) {
    unsigned a = 0u, c = (unsigned)it;
    tf2x32(0u, 42u, a, c);
    fk0[it] = a; fk1[it] = c;
  }

  // ---- CSR build + agg zeroing ----
  hipMemsetAsync(off_r, 0, 2 * 8192 * sizeof(int), stream);
  hist_kern<<<512, 256, 0, stream>>>(ei_r, ei_p, off_r, off_p, agg_r);
  scan_kern<<<2, 256, 0, stream>>>(off_r, off_p);
  scatter_kern<<<512, 256, 0, stream>>>(ei_r, ei_p, off_r, off_p,
                                        perm_r, perm_p, srcs_r, srcs_p,
                                        dsts_r, dsts_p);

  // ---- gnn1 ----
  msg_gemm<64><<<2048, 256, 0, stream>>>(x_r, ef_r, srcs_r, perm_r, dsts_r, agg_r,
                                         x_p, ef_p, srcs_p, perm_p, dsts_p, agg_p,
                                         g1_Wm, g1_We);
  node1_gemm<<<256, 256, 0, stream>>>(x_r, agg_r, h_r, x_p, agg_p, h_p, g1_Ws, g1_b);
  mhat_soft<<<512, 256, 0, stream>>>(h_r, h_p, Mhat, Msoft, out, rfr, fk0[0], fk1[0]);

  for (int it = 0; it < 3; ++it) {
    rfp_kern<<<512, 256, 0, stream>>>(Msoft, rfr, rfp);
    msg_gemm<32><<<2048, 256, 0, stream>>>(rfr, ef_r, srcs_r, perm_r, dsts_r, agg_r,
                                           rfp, ef_p, srcs_p, perm_p, dsts_p, agg_p,
                                           g2_Wm, g2_We);
    node2u_gemm<<<256, 256, 0, stream>>>(rfr, agg_r, u_r, rfp, agg_p, u_p,
                                         g2_Ws, g2_b, W1, b1);
    int last = (it == 2);
    upd_soft<<<512, 256, 0, stream>>>(u_r, u_p, W2, b2, Mhat,
                                      last ? (out + 1048576) : Msoft,
                                      /*writeMhat=*/!last,
                                      rfr, /*doRng=*/!last,
                                      fk0[it < 2 ? it + 1 : 0], fk1[it < 2 ? it + 1 : 0]);
  }
}